// Round 3
// baseline (4821.894 us; speedup 1.0000x reference)
//
#include <hip/hip_runtime.h>
#include <math.h>

#define N0 100000
#define N1 20000
#define N2 4000
#define FDIM 128
#define HDIM 128
#define CDIM 10
#define E0C 1600000
#define E1C 320000
#define E2C 64000
#define EPSBN 1e-5f

// ---------------- small utility kernels ----------------

__global__ void fill_kernel(float* __restrict__ p, float v, int n) {
    int i = blockIdx.x * blockDim.x + threadIdx.x;
    if (i < n) p[i] = v;
}

__global__ void deg_accum_kernel(const int* __restrict__ col, float* __restrict__ deg, int e) {
    int i = blockIdx.x * blockDim.x + threadIdx.x;
    if (i < e) atomicAdd(&deg[col[i]], 1.0f);
}

__global__ void rsqrt_kernel(float* __restrict__ p, int n) {
    int i = blockIdx.x * blockDim.x + threadIdx.x;
    if (i < n) p[i] = rsqrtf(p[i]);
}

// scale = gamma * rsqrt(var+eps); shift = beta - mean*scale   (4*128 entries)
__global__ void bn_pre_kernel(const float* __restrict__ g, const float* __restrict__ beta,
                              const float* __restrict__ mean, const float* __restrict__ var,
                              float* __restrict__ scale, float* __restrict__ shift) {
    int i = blockIdx.x * blockDim.x + threadIdx.x;
    if (i < 4 * HDIM) {
        float s = g[i] * rsqrtf(var[i] + EPSBN);
        scale[i] = s;
        shift[i] = beta[i] - mean[i] * s;
    }
}

// ---------------- matmul K=128, N=128 with fused epilogues ----------------
// out[row][col] = f( A[row]@W[.,col] (+ gsrc[gidx[row]][col]) )
// pool==1: t=relu(acc+bias[col]); t=t*bnscale[col]+bnshift[col]; t=relu(t)
// dis!=null: multiply by dis[row]
// LDS: W streamed in two 64x128 chunks (32 KiB) + full A tile (10 KiB) = 43 KiB < 64 KiB limit.
#define MM_ROWS 16
__global__ __launch_bounds__(256) void mm128_kernel(
    const float* __restrict__ A, const float* __restrict__ W,
    float* __restrict__ out, int M,
    const float* __restrict__ dis,
    const float* __restrict__ gsrc, const int* __restrict__ gidx,
    const float* __restrict__ bias,
    const float* __restrict__ bnscale, const float* __restrict__ bnshift,
    int pool)
{
    __shared__ float Ws[64 * 128];   // one K-chunk of W
    __shared__ float As[128 * 20];   // transposed A tile [k][r], 16 rows padded to 20
    int tid = threadIdx.x;

    int rowBase = blockIdx.x * MM_ROWS;
    {
        int k = tid & 127;
        int r0 = tid >> 7;  // 0..1
        #pragma unroll
        for (int i = 0; i < MM_ROWS; i += 2) {
            int r = r0 + i;
            int row = rowBase + r;
            float v = (row < M) ? A[(long long)row * 128 + k] : 0.0f;
            As[k * 20 + r] = v;
        }
    }

    int col = tid & 127;
    int rsub = tid >> 7;  // thread covers rows rsub*8 .. rsub*8+7
    float acc[8] = {0, 0, 0, 0, 0, 0, 0, 0};

    #pragma unroll
    for (int chunk = 0; chunk < 2; chunk++) {
        __syncthreads();  // iter0: As ready / Ws free; iter1: previous chunk consumed
        // load W rows [chunk*64, chunk*64+64) : 64*128 floats = 2048 float4, 8 per thread
        const float4* wsrc = (const float4*)(W + chunk * 64 * 128);
        #pragma unroll
        for (int i = 0; i < 8; i++)
            ((float4*)Ws)[tid + i * 256] = wsrc[tid + i * 256];
        __syncthreads();

        int kbase = chunk * 64;
        #pragma unroll 8
        for (int kk = 0; kk < 64; kk++) {
            float w = Ws[kk * 128 + col];
            const float* ap = &As[(kbase + kk) * 20 + rsub * 8];
            float4 a0 = *(const float4*)(ap);
            float4 a1 = *(const float4*)(ap + 4);
            acc[0] += a0.x * w; acc[1] += a0.y * w; acc[2] += a0.z * w; acc[3] += a0.w * w;
            acc[4] += a1.x * w; acc[5] += a1.y * w; acc[6] += a1.z * w; acc[7] += a1.w * w;
        }
    }

    float bcol = 0.f, scol = 0.f, hcol = 0.f;
    if (pool) { bcol = bias[col]; scol = bnscale[col]; hcol = bnshift[col]; }

    #pragma unroll
    for (int i = 0; i < 8; i++) {
        int row = rowBase + rsub * 8 + i;
        if (row >= M) break;
        float v = acc[i];
        if (gsrc) v += gsrc[(long long)gidx[row] * 128 + col];
        if (pool) {
            v = fmaxf(v + bcol, 0.f);
            v = v * scol + hcol;
            v = fmaxf(v, 0.f);
        }
        if (dis) v *= dis[row];
        out[(long long)row * 128 + col] = v;
    }
}

// ---------------- matmul K=128, N=10 (one thread per row) ----------------
__global__ __launch_bounds__(256) void mm10_kernel(
    const float* __restrict__ A, const float* __restrict__ W,  // W [128,10]
    float* __restrict__ out, int M,
    const float* __restrict__ dis,
    const float* __restrict__ gsrc, const int* __restrict__ gidx)
{
    __shared__ float Ws[128 * 10];
    for (int i = threadIdx.x; i < 1280; i += 256) Ws[i] = W[i];
    __syncthreads();
    int row = blockIdx.x * blockDim.x + threadIdx.x;
    if (row >= M) return;
    const float4* a = (const float4*)(A + (long long)row * 128);
    float acc[10] = {0, 0, 0, 0, 0, 0, 0, 0, 0, 0};
    #pragma unroll 4
    for (int k4 = 0; k4 < 32; k4++) {
        float4 av = a[k4];
        int k = k4 * 4;
        #pragma unroll
        for (int c = 0; c < 10; c++) {
            acc[c] += av.x * Ws[(k + 0) * 10 + c] + av.y * Ws[(k + 1) * 10 + c]
                    + av.z * Ws[(k + 2) * 10 + c] + av.w * Ws[(k + 3) * 10 + c];
        }
    }
    float d = dis ? dis[row] : 1.0f;
    const float* g = gsrc ? (gsrc + (long long)gidx[row] * 10) : nullptr;
    #pragma unroll
    for (int c = 0; c < 10; c++) {
        float v = acc[c];
        if (g) v += g[c];
        out[(long long)row * 10 + c] = v * d;
    }
}

// ---------------- scatter kernels ----------------

// z[col[e]] += y[row[e]]  over 128 features (float4 per thread)
__global__ void edge_scatter128_kernel(const int* __restrict__ rows, const int* __restrict__ cols,
                                       const float* __restrict__ y, float* __restrict__ z, long long E) {
    long long i = (long long)blockIdx.x * blockDim.x + threadIdx.x;
    if (i >= E * 32) return;
    int e = (int)(i >> 5);
    int f4 = (int)(i & 31);
    int r = rows[e], c = cols[e];
    float4 v = ((const float4*)(y + (long long)r * 128))[f4];
    float* dst = z + (long long)c * 128 + (long long)f4 * 4;
    atomicAdd(dst + 0, v.x);
    atomicAdd(dst + 1, v.y);
    atomicAdd(dst + 2, v.z);
    atomicAdd(dst + 3, v.w);
}

// p[parent[node]] += h[node]  over 128 features
__global__ void node_scatter128_kernel(const int* __restrict__ parent, const float* __restrict__ h,
                                       float* __restrict__ p, long long n) {
    long long i = (long long)blockIdx.x * blockDim.x + threadIdx.x;
    if (i >= n * 32) return;
    int node = (int)(i >> 5);
    int f4 = (int)(i & 31);
    float4 v = ((const float4*)(h + (long long)node * 128))[f4];
    float* dst = p + (long long)parent[node] * 128 + (long long)f4 * 4;
    atomicAdd(dst + 0, v.x);
    atomicAdd(dst + 1, v.y);
    atomicAdd(dst + 2, v.z);
    atomicAdd(dst + 3, v.w);
}

// z[col[e]] += y[row[e]] over 10 features
__global__ void edge_scatter10_kernel(const int* __restrict__ rows, const int* __restrict__ cols,
                                      const float* __restrict__ y, float* __restrict__ z, long long E) {
    long long i = (long long)blockIdx.x * blockDim.x + threadIdx.x;
    if (i >= E * 10) return;
    int e = (int)(i / 10);
    int f = (int)(i - (long long)e * 10);
    atomicAdd(&z[(long long)cols[e] * 10 + f], y[(long long)rows[e] * 10 + f]);
}

// h = relu(dis*(z+y) + b), 128 features, float4 per thread
__global__ void gcn_ep_kernel(const float* __restrict__ z, const float* __restrict__ y,
                              const float* __restrict__ dis, const float* __restrict__ bias,
                              float* __restrict__ h, long long n) {
    long long i = (long long)blockIdx.x * blockDim.x + threadIdx.x;
    if (i >= n * 32) return;
    int row = (int)(i >> 5);
    int f4 = (int)(i & 31);
    float4 zv = ((const float4*)z)[i];
    float4 yv = ((const float4*)y)[i];
    float4 b = ((const float4*)bias)[f4];
    float d = dis[row];
    float4 r;
    r.x = fmaxf(fmaf(d, zv.x + yv.x, b.x), 0.f);
    r.y = fmaxf(fmaf(d, zv.y + yv.y, b.y), 0.f);
    r.z = fmaxf(fmaf(d, zv.z + yv.z, b.z), 0.f);
    r.w = fmaxf(fmaf(d, zv.w + yv.w, b.w), 0.f);
    ((float4*)h)[i] = r;
}

// final epilogue: v = dis*(z+y)+b over 10 classes, then log_softmax
__global__ void lsm_kernel(const float* __restrict__ z, const float* __restrict__ y,
                           const float* __restrict__ dis, const float* __restrict__ bias,
                           float* __restrict__ out, int n) {
    int row = blockIdx.x * blockDim.x + threadIdx.x;
    if (row >= n) return;
    float d = dis[row];
    float v[10];
    float m = -1e30f;
    #pragma unroll
    for (int c = 0; c < 10; c++) {
        float t = fmaf(d, z[(long long)row * 10 + c] + y[(long long)row * 10 + c], bias[c]);
        v[c] = t;
        m = fmaxf(m, t);
    }
    float s = 0.f;
    #pragma unroll
    for (int c = 0; c < 10; c++) s += expf(v[c] - m);
    float ls = logf(s);
    #pragma unroll
    for (int c = 0; c < 10; c++) out[(long long)row * 10 + c] = v[c] - m - ls;
}

// ---------------- launcher ----------------

extern "C" void kernel_launch(void* const* d_in, const int* in_sizes, int n_in,
                              void* d_out, int out_size, void* d_ws, size_t ws_size,
                              hipStream_t stream) {
    const float* x       = (const float*)d_in[0];
    const int*   ei0     = (const int*)d_in[1];
    const int*   ei1     = (const int*)d_in[2];
    const int*   ei2     = (const int*)d_in[3];
    const int*   parent1 = (const int*)d_in[4];
    const int*   parent2 = (const int*)d_in[5];
    const float* W0 = (const float*)d_in[6];
    const float* b0 = (const float*)d_in[7];
    const float* W1 = (const float*)d_in[8];
    const float* b1 = (const float*)d_in[9];
    const float* W2 = (const float*)d_in[10];
    const float* b2 = (const float*)d_in[11];
    const float* W3 = (const float*)d_in[12];
    const float* b3 = (const float*)d_in[13];
    const float* W4 = (const float*)d_in[14];
    const float* b4 = (const float*)d_in[15];
    const float* pW = (const float*)d_in[16];
    const float* pb = (const float*)d_in[17];
    const float* pg = (const float*)d_in[18];
    const float* pbeta = (const float*)d_in[19];
    const float* pmean = (const float*)d_in[20];
    const float* pvar  = (const float*)d_in[21];
    float* out = (float*)d_out;

    char* ws = (char*)d_ws;
    size_t off = 0;
    auto alloc = [&](size_t nfloats) -> float* {
        float* p = (float*)(ws + off);
        off += ((nfloats * 4 + 255) / 256) * 256;
        return p;
    };
    float* dis0 = alloc(N0);
    float* dis1 = alloc(N1);
    float* dis2 = alloc(N2);
    float* bnscale = alloc(4 * HDIM);
    float* bnshift = alloc(4 * HDIM);
    float* Y   = alloc((size_t)N0 * 128);
    float* Z   = alloc((size_t)N0 * 128);
    float* H0  = alloc((size_t)N0 * 128);
    float* H1  = alloc((size_t)N1 * 128);
    float* P   = alloc((size_t)N1 * 128);
    float* X1  = alloc((size_t)N1 * 128);
    float* HU1 = alloc((size_t)N1 * 128);
    float* U1  = alloc((size_t)N1 * 128);
    float* X2  = alloc((size_t)N2 * 128);
    float* H2  = alloc((size_t)N2 * 128);
    float* U2  = alloc((size_t)N2 * 128);
    float* V2  = alloc((size_t)N2 * 128);
    float* W1b = alloc((size_t)N1 * 10);
    float* Y4  = alloc((size_t)N0 * 10);
    float* Z4  = alloc((size_t)N0 * 10);

    const int B = 256;
    auto G = [](long long t) { return (unsigned)((t + 255) / 256); };

    // degrees -> dis = deg^-1/2  (deg = 1 self loop + incoming count on col)
    fill_kernel<<<G(N0), B, 0, stream>>>(dis0, 1.0f, N0);
    fill_kernel<<<G(N1), B, 0, stream>>>(dis1, 1.0f, N1);
    fill_kernel<<<G(N2), B, 0, stream>>>(dis2, 1.0f, N2);
    deg_accum_kernel<<<G(E0C), B, 0, stream>>>(ei0 + E0C, dis0, E0C);
    deg_accum_kernel<<<G(E1C), B, 0, stream>>>(ei1 + E1C, dis1, E1C);
    deg_accum_kernel<<<G(E2C), B, 0, stream>>>(ei2 + E2C, dis2, E2C);
    rsqrt_kernel<<<G(N0), B, 0, stream>>>(dis0, N0);
    rsqrt_kernel<<<G(N1), B, 0, stream>>>(dis1, N1);
    rsqrt_kernel<<<G(N2), B, 0, stream>>>(dis2, N2);
    bn_pre_kernel<<<2, B, 0, stream>>>(pg, pbeta, pmean, pvar, bnscale, bnshift);

    // ---- gcn0: h0 = relu(gcn(x, ei0, W0, b0)) ----
    mm128_kernel<<<(N0 + 15) / 16, B, 0, stream>>>(
        x, W0, Y, N0, dis0, nullptr, nullptr, nullptr, nullptr, nullptr, 0);
    (void)hipMemsetAsync(Z, 0, (size_t)N0 * 128 * 4, stream);
    edge_scatter128_kernel<<<G((long long)E0C * 32), B, 0, stream>>>(ei0, ei0 + E0C, Y, Z, E0C);
    gcn_ep_kernel<<<G((long long)N0 * 32), B, 0, stream>>>(Z, Y, dis0, b0, H0, N0);

    // ---- pool1: p = segsum(h0, parent1); x1 = relu(pool_nn(p, level0)) ----
    (void)hipMemsetAsync(P, 0, (size_t)N1 * 128 * 4, stream);
    node_scatter128_kernel<<<G((long long)N0 * 32), B, 0, stream>>>(parent1, H0, P, N0);
    mm128_kernel<<<(N1 + 15) / 16, B, 0, stream>>>(
        P, pW, X1, N1, nullptr, nullptr, nullptr, pb, bnscale, bnshift, 1);

    // ---- gcn1: h1 = relu(gcn(x1, ei1, W1, b1)) ----
    mm128_kernel<<<(N1 + 15) / 16, B, 0, stream>>>(
        X1, W1, Y, N1, dis1, nullptr, nullptr, nullptr, nullptr, nullptr, 0);
    (void)hipMemsetAsync(Z, 0, (size_t)N1 * 128 * 4, stream);
    edge_scatter128_kernel<<<G((long long)E1C * 32), B, 0, stream>>>(ei1, ei1 + E1C, Y, Z, E1C);
    gcn_ep_kernel<<<G((long long)N1 * 32), B, 0, stream>>>(Z, Y, dis1, b1, H1, N1);

    // ---- pool2: p = segsum(h1, parent2); x2 = relu(pool_nn(p, level1)) ----
    (void)hipMemsetAsync(P, 0, (size_t)N2 * 128 * 4, stream);
    node_scatter128_kernel<<<G((long long)N1 * 32), B, 0, stream>>>(parent2, H1, P, N1);
    mm128_kernel<<<(N2 + 15) / 16, B, 0, stream>>>(
        P, pW + 128 * 128, X2, N2, nullptr, nullptr, nullptr, pb + 128, bnscale + 128, bnshift + 128, 1);

    // ---- gcn2: h2 = relu(gcn(x2, ei2, W2, b2)) ----
    mm128_kernel<<<(N2 + 15) / 16, B, 0, stream>>>(
        X2, W2, Y, N2, dis2, nullptr, nullptr, nullptr, nullptr, nullptr, 0);
    (void)hipMemsetAsync(Z, 0, (size_t)N2 * 128 * 4, stream);
    edge_scatter128_kernel<<<G((long long)E2C * 32), B, 0, stream>>>(ei2, ei2 + E2C, Y, Z, E2C);
    gcn_ep_kernel<<<G((long long)N2 * 32), B, 0, stream>>>(Z, Y, dis2, b2, H2, N2);

    // ---- up level 2: u2 = relu(pool_nn(h2, level2)); v2 = u2 @ W3_top ----
    mm128_kernel<<<(N2 + 15) / 16, B, 0, stream>>>(
        H2, pW + 2 * 128 * 128, U2, N2, nullptr, nullptr, nullptr, pb + 256, bnscale + 256, bnshift + 256, 1);
    mm128_kernel<<<(N2 + 15) / 16, B, 0, stream>>>(
        U2, W3, V2, N2, nullptr, nullptr, nullptr, nullptr, nullptr, nullptr, 0);

    // ---- gcn3: y = dis1 * (v2[parent2] + h1 @ W3_bot); aggregate over ei1 ----
    mm128_kernel<<<(N1 + 15) / 16, B, 0, stream>>>(
        H1, W3 + 128 * 128, Y, N1, dis1, V2, parent2, nullptr, nullptr, nullptr, 0);
    (void)hipMemsetAsync(Z, 0, (size_t)N1 * 128 * 4, stream);
    edge_scatter128_kernel<<<G((long long)E1C * 32), B, 0, stream>>>(ei1, ei1 + E1C, Y, Z, E1C);
    gcn_ep_kernel<<<G((long long)N1 * 32), B, 0, stream>>>(Z, Y, dis1, b3, HU1, N1);

    // ---- up level 1: u1 = relu(pool_nn(hu1, level3)); w1 = u1 @ W4_top [N1,10] ----
    mm128_kernel<<<(N1 + 15) / 16, B, 0, stream>>>(
        HU1, pW + 3 * 128 * 128, U1, N1, nullptr, nullptr, nullptr, pb + 384, bnscale + 384, bnshift + 384, 1);
    mm10_kernel<<<G(N1), B, 0, stream>>>(U1, W4, W1b, N1, nullptr, nullptr, nullptr);

    // ---- gcn4: y4 = dis0 * (w1[parent1] + h0 @ W4_bot); aggregate over ei0; log_softmax ----
    mm10_kernel<<<G(N0), B, 0, stream>>>(H0, W4 + 128 * 10, Y4, N0, dis0, W1b, parent1);
    (void)hipMemsetAsync(Z4, 0, (size_t)N0 * 10 * 4, stream);
    edge_scatter10_kernel<<<G((long long)E0C * 10), B, 0, stream>>>(ei0, ei0 + E0C, Y4, Z4, E0C);
    lsm_kernel<<<G(N0), B, 0, stream>>>(Z4, Y4, dis0, b4, out, N0);
}

// Round 5
// 1139.646 us; speedup vs baseline: 4.2310x; 4.2310x over previous
//
#include <hip/hip_runtime.h>
#include <math.h>

#define N0 100000
#define N1 20000
#define N2 4000
#define HDIM 128
#define E0C 1600000
#define E1C 320000
#define E2C 64000
#define EPSBN 1e-5f

// ---------------- CSR build kernels ----------------

__global__ void count_kernel(const int* __restrict__ idx, int* __restrict__ cnt, int n) {
    int i = blockIdx.x * blockDim.x + threadIdx.x;
    if (i < n) atomicAdd(&cnt[idx[i]], 1);
}

// dis = (cnt+1)^-1/2   (self loop included in degree)
__global__ void dis_kernel(const int* __restrict__ cnt, float* __restrict__ dis, int n) {
    int i = blockIdx.x * blockDim.x + threadIdx.x;
    if (i < n) dis[i] = rsqrtf((float)(cnt[i] + 1));
}

// One workgroup (1024 thr) per array: exclusive prefix sum of cnt -> rp[0..n], and mirror into cur[0..n-1].
__global__ __launch_bounds__(1024) void scan5_kernel(
    const int* c0, int* r0, int* u0, int n0,
    const int* c1, int* r1, int* u1, int n1,
    const int* c2, int* r2, int* u2, int n2,
    const int* c3, int* r3, int* u3, int n3,
    const int* c4, int* r4, int* u4, int n4)
{
    const int* c; int* r; int* u; int n;
    switch (blockIdx.x) {
        case 0: c = c0; r = r0; u = u0; n = n0; break;
        case 1: c = c1; r = r1; u = u1; n = n1; break;
        case 2: c = c2; r = r2; u = u2; n = n2; break;
        case 3: c = c3; r = r3; u = u3; n = n3; break;
        default: c = c4; r = r4; u = u4; n = n4; break;
    }
    __shared__ int ts[1024];
    int t = threadIdx.x;
    int per = (n + 1023) >> 10;
    int start = t * per;
    int local = 0;
    for (int i = 0; i < per; i++) {
        int idx = start + i;
        if (idx < n) local += c[idx];
    }
    ts[t] = local;
    __syncthreads();
    for (int o = 1; o < 1024; o <<= 1) {
        int v = (t >= o) ? ts[t - o] : 0;
        __syncthreads();
        ts[t] += v;
        __syncthreads();
    }
    int run = (t == 0) ? 0 : ts[t - 1];
    for (int i = 0; i < per; i++) {
        int idx = start + i;
        if (idx < n) {
            r[idx] = run;
            u[idx] = run;
            run += c[idx];
        }
    }
    if (t == 0) r[n] = ts[1023];
}

// srcl[pos] = rows[e], bucketed by cols[e]
__global__ void fill_edges_kernel(const int* __restrict__ rows, const int* __restrict__ cols,
                                  int* __restrict__ cur, int* __restrict__ srcl, int E) {
    int e = blockIdx.x * blockDim.x + threadIdx.x;
    if (e < E) {
        int pos = atomicAdd(&cur[cols[e]], 1);
        srcl[pos] = rows[e];
    }
}

__global__ void fill_parent_kernel(const int* __restrict__ parent,
                                   int* __restrict__ cur, int* __restrict__ childl, int n) {
    int i = blockIdx.x * blockDim.x + threadIdx.x;
    if (i < n) {
        int pos = atomicAdd(&cur[parent[i]], 1);
        childl[pos] = i;
    }
}

// scale = gamma * rsqrt(var+eps); shift = beta - mean*scale
__global__ void bn_pre_kernel(const float* __restrict__ g, const float* __restrict__ beta,
                              const float* __restrict__ mean, const float* __restrict__ var,
                              float* __restrict__ scale, float* __restrict__ shift) {
    int i = blockIdx.x * blockDim.x + threadIdx.x;
    if (i < 4 * HDIM) {
        float s = g[i] * rsqrtf(var[i] + EPSBN);
        scale[i] = s;
        shift[i] = beta[i] - mean[i] * s;
    }
}

// ---------------- gather kernels (no atomics) ----------------

// One wave per destination node. h[c] = relu(dis[c] * (y[c] + sum_{e in CSR[c]} y[src_e]) + bias)
__global__ __launch_bounds__(256) void gather128_kernel(
    const int* __restrict__ rp, const int* __restrict__ srcl,
    const float* __restrict__ y, const float* __restrict__ dis,
    const float* __restrict__ bias, float* __restrict__ h, int n)
{
    int wid = (int)((blockIdx.x * 256 + threadIdx.x) >> 6);  // destination node
    int lane = threadIdx.x & 63;
    if (wid >= n) return;
    const float2* y2 = (const float2*)y;
    float2 acc = y2[(long long)wid * 64 + lane];  // self loop
    int e = rp[wid], e1 = rp[wid + 1];
    for (; e + 1 < e1; e += 2) {
        int s0 = srcl[e], s1 = srcl[e + 1];
        float2 v0 = y2[(long long)s0 * 64 + lane];
        float2 v1 = y2[(long long)s1 * 64 + lane];
        acc.x += v0.x + v1.x;
        acc.y += v0.y + v1.y;
    }
    if (e < e1) {
        int s = srcl[e];
        float2 v = y2[(long long)s * 64 + lane];
        acc.x += v.x; acc.y += v.y;
    }
    float d = dis[wid];
    float2 b = ((const float2*)bias)[lane];
    float2 r;
    r.x = fmaxf(fmaf(d, acc.x, b.x), 0.f);
    r.y = fmaxf(fmaf(d, acc.y, b.y), 0.f);
    ((float2*)h)[(long long)wid * 64 + lane] = r;
}

// Pool segment-sum: p[parent] = sum of h[children]   (one wave per parent)
__global__ __launch_bounds__(256) void gatherP_kernel(
    const int* __restrict__ pp, const int* __restrict__ childl,
    const float* __restrict__ h, float* __restrict__ p, int n)
{
    int wid = (int)((blockIdx.x * 256 + threadIdx.x) >> 6);
    int lane = threadIdx.x & 63;
    if (wid >= n) return;
    const float2* h2 = (const float2*)h;
    float2 acc = make_float2(0.f, 0.f);
    int e = pp[wid], e1 = pp[wid + 1];
    for (; e + 1 < e1; e += 2) {
        int s0 = childl[e], s1 = childl[e + 1];
        float2 v0 = h2[(long long)s0 * 64 + lane];
        float2 v1 = h2[(long long)s1 * 64 + lane];
        acc.x += v0.x + v1.x;
        acc.y += v0.y + v1.y;
    }
    if (e < e1) {
        int s = childl[e];
        float2 v = h2[(long long)s * 64 + lane];
        acc.x += v.x; acc.y += v.y;
    }
    ((float2*)p)[(long long)wid * 64 + lane] = acc;
}

// Final: gather 10-wide + bias + log_softmax, one thread per destination node
__global__ __launch_bounds__(256) void gather10_lsm_kernel(
    const int* __restrict__ rp, const int* __restrict__ srcl,
    const float* __restrict__ y4, const float* __restrict__ dis,
    const float* __restrict__ bias, float* __restrict__ out, int n)
{
    int c = blockIdx.x * blockDim.x + threadIdx.x;
    if (c >= n) return;
    const float2* y2 = (const float2*)y4;  // rows are 5 float2
    float acc[10];
    {
        long long base = (long long)c * 5;
        #pragma unroll
        for (int j = 0; j < 5; j++) {
            float2 v = y2[base + j];
            acc[2 * j] = v.x; acc[2 * j + 1] = v.y;
        }
    }
    int e0 = rp[c], e1 = rp[c + 1];
    for (int e = e0; e < e1; e++) {
        long long base = (long long)srcl[e] * 5;
        #pragma unroll
        for (int j = 0; j < 5; j++) {
            float2 v = y2[base + j];
            acc[2 * j] += v.x; acc[2 * j + 1] += v.y;
        }
    }
    float d = dis[c];
    float m = -1e30f;
    #pragma unroll
    for (int k = 0; k < 10; k++) {
        acc[k] = fmaf(d, acc[k], bias[k]);
        m = fmaxf(m, acc[k]);
    }
    float s = 0.f;
    #pragma unroll
    for (int k = 0; k < 10; k++) s += expf(acc[k] - m);
    float ls = logf(s);
    #pragma unroll
    for (int k = 0; k < 10; k++) out[(long long)c * 10 + k] = acc[k] - m - ls;
}

// ---------------- matmul K=128, N=128 with fused epilogues ----------------
#define MM_ROWS 16
__global__ __launch_bounds__(256) void mm128_kernel(
    const float* __restrict__ A, const float* __restrict__ W,
    float* __restrict__ out, int M,
    const float* __restrict__ dis,
    const float* __restrict__ gsrc, const int* __restrict__ gidx,
    const float* __restrict__ bias,
    const float* __restrict__ bnscale, const float* __restrict__ bnshift,
    int pool)
{
    __shared__ float Ws[64 * 128];   // one K-chunk of W (two chunks streamed)
    __shared__ float As[128 * 20];   // transposed A tile [k][r], 16 rows padded to 20
    int tid = threadIdx.x;

    int rowBase = blockIdx.x * MM_ROWS;
    {
        int k = tid & 127;
        int r0 = tid >> 7;
        #pragma unroll
        for (int i = 0; i < MM_ROWS; i += 2) {
            int r = r0 + i;
            int row = rowBase + r;
            float v = (row < M) ? A[(long long)row * 128 + k] : 0.0f;
            As[k * 20 + r] = v;
        }
    }

    int col = tid & 127;
    int rsub = tid >> 7;
    float acc[8] = {0, 0, 0, 0, 0, 0, 0, 0};

    #pragma unroll
    for (int chunk = 0; chunk < 2; chunk++) {
        __syncthreads();
        const float4* wsrc = (const float4*)(W + chunk * 64 * 128);
        #pragma unroll
        for (int i = 0; i < 8; i++)
            ((float4*)Ws)[tid + i * 256] = wsrc[tid + i * 256];
        __syncthreads();

        int kbase = chunk * 64;
        #pragma unroll 8
        for (int kk = 0; kk < 64; kk++) {
            float w = Ws[kk * 128 + col];
            const float* ap = &As[(kbase + kk) * 20 + rsub * 8];
            float4 a0 = *(const float4*)(ap);
            float4 a1 = *(const float4*)(ap + 4);
            acc[0] += a0.x * w; acc[1] += a0.y * w; acc[2] += a0.z * w; acc[3] += a0.w * w;
            acc[4] += a1.x * w; acc[5] += a1.y * w; acc[6] += a1.z * w; acc[7] += a1.w * w;
        }
    }

    float bcol = 0.f, scol = 0.f, hcol = 0.f;
    if (pool) { bcol = bias[col]; scol = bnscale[col]; hcol = bnshift[col]; }

    #pragma unroll
    for (int i = 0; i < 8; i++) {
        int row = rowBase + rsub * 8 + i;
        if (row >= M) break;
        float v = acc[i];
        if (gsrc) v += gsrc[(long long)gidx[row] * 128 + col];
        if (pool) {
            v = fmaxf(v + bcol, 0.f);
            v = v * scol + hcol;
            v = fmaxf(v, 0.f);
        }
        if (dis) v *= dis[row];
        out[(long long)row * 128 + col] = v;
    }
}

// ---------------- matmul K=128, N=10 (one thread per row) ----------------
__global__ __launch_bounds__(256) void mm10_kernel(
    const float* __restrict__ A, const float* __restrict__ W,  // W [128,10]
    float* __restrict__ out, int M,
    const float* __restrict__ dis,
    const float* __restrict__ gsrc, const int* __restrict__ gidx)
{
    __shared__ float Ws[128 * 10];
    for (int i = threadIdx.x; i < 1280; i += 256) Ws[i] = W[i];
    __syncthreads();
    int row = blockIdx.x * blockDim.x + threadIdx.x;
    if (row >= M) return;
    const float4* a = (const float4*)(A + (long long)row * 128);
    float acc[10] = {0, 0, 0, 0, 0, 0, 0, 0, 0, 0};
    #pragma unroll 4
    for (int k4 = 0; k4 < 32; k4++) {
        float4 av = a[k4];
        int k = k4 * 4;
        #pragma unroll
        for (int c = 0; c < 10; c++) {
            acc[c] += av.x * Ws[(k + 0) * 10 + c] + av.y * Ws[(k + 1) * 10 + c]
                    + av.z * Ws[(k + 2) * 10 + c] + av.w * Ws[(k + 3) * 10 + c];
        }
    }
    float d = dis ? dis[row] : 1.0f;
    const float* g = gsrc ? (gsrc + (long long)gidx[row] * 10) : nullptr;
    #pragma unroll
    for (int c = 0; c < 10; c++) {
        float v = acc[c];
        if (g) v += g[c];
        out[(long long)row * 10 + c] = v * d;
    }
}

// ---------------- launcher ----------------

extern "C" void kernel_launch(void* const* d_in, const int* in_sizes, int n_in,
                              void* d_out, int out_size, void* d_ws, size_t ws_size,
                              hipStream_t stream) {
    const float* x       = (const float*)d_in[0];
    const int*   ei0     = (const int*)d_in[1];
    const int*   ei1     = (const int*)d_in[2];
    const int*   ei2     = (const int*)d_in[3];
    const int*   parent1 = (const int*)d_in[4];
    const int*   parent2 = (const int*)d_in[5];
    const float* W0 = (const float*)d_in[6];
    const float* b0 = (const float*)d_in[7];
    const float* W1 = (const float*)d_in[8];
    const float* b1 = (const float*)d_in[9];
    const float* W2 = (const float*)d_in[10];
    const float* b2 = (const float*)d_in[11];
    const float* W3 = (const float*)d_in[12];
    const float* b3 = (const float*)d_in[13];
    const float* W4 = (const float*)d_in[14];
    const float* b4 = (const float*)d_in[15];
    const float* pW = (const float*)d_in[16];
    const float* pb = (const float*)d_in[17];
    const float* pg = (const float*)d_in[18];
    const float* pbeta = (const float*)d_in[19];
    const float* pmean = (const float*)d_in[20];
    const float* pvar  = (const float*)d_in[21];
    float* out = (float*)d_out;

    char* ws = (char*)d_ws;
    size_t off = 0;
    auto alloc = [&](size_t nbytes) -> char* {
        char* p = ws + off;
        off += ((nbytes + 255) / 256) * 256;
        return p;
    };
    // float buffers
    float* dis0 = (float*)alloc(N0 * 4);
    float* dis1 = (float*)alloc(N1 * 4);
    float* dis2 = (float*)alloc(N2 * 4);
    float* bnscale = (float*)alloc(4 * HDIM * 4);
    float* bnshift = (float*)alloc(4 * HDIM * 4);
    float* Y   = (float*)alloc((size_t)N0 * 128 * 4);
    float* H0  = (float*)alloc((size_t)N0 * 128 * 4);
    float* H1  = (float*)alloc((size_t)N1 * 128 * 4);
    float* P   = (float*)alloc((size_t)N1 * 128 * 4);
    float* X1  = (float*)alloc((size_t)N1 * 128 * 4);
    float* HU1 = (float*)alloc((size_t)N1 * 128 * 4);
    float* U1  = (float*)alloc((size_t)N1 * 128 * 4);
    float* X2  = (float*)alloc((size_t)N2 * 128 * 4);
    float* H2  = (float*)alloc((size_t)N2 * 128 * 4);
    float* U2  = (float*)alloc((size_t)N2 * 128 * 4);
    float* V2  = (float*)alloc((size_t)N2 * 128 * 4);
    float* W1b = (float*)alloc((size_t)N1 * 10 * 4);
    float* Y4  = (float*)alloc((size_t)N0 * 10 * 4);
    // int buffers: counts contiguous (single memset)
    const int CNT_TOTAL = N0 + N1 + N2 + N1 + N2;
    int* cntBase = (int*)alloc((size_t)CNT_TOTAL * 4);
    int* cnt0  = cntBase;
    int* cnt1  = cnt0 + N0;
    int* cnt2  = cnt1 + N1;
    int* pcnt1 = cnt2 + N2;
    int* pcnt2 = pcnt1 + N1;
    int* rp0 = (int*)alloc((N0 + 1) * 4);
    int* rp1 = (int*)alloc((N1 + 1) * 4);
    int* rp2 = (int*)alloc((N2 + 1) * 4);
    int* pp1 = (int*)alloc((N1 + 1) * 4);
    int* pp2 = (int*)alloc((N2 + 1) * 4);
    int* cur0  = (int*)alloc(N0 * 4);
    int* cur1  = (int*)alloc(N1 * 4);
    int* cur2  = (int*)alloc(N2 * 4);
    int* pcur1 = (int*)alloc(N1 * 4);
    int* pcur2 = (int*)alloc(N2 * 4);
    int* src0   = (int*)alloc((size_t)E0C * 4);
    int* src1   = (int*)alloc((size_t)E1C * 4);
    int* src2   = (int*)alloc((size_t)E2C * 4);
    int* child1 = (int*)alloc((size_t)N0 * 4);
    int* child2 = (int*)alloc((size_t)N1 * 4);

    const int B = 256;
    auto G = [](long long t) { return (unsigned)((t + 255) / 256); };

    // ---- CSR build ----
    (void)hipMemsetAsync(cntBase, 0, (size_t)CNT_TOTAL * 4, stream);
    count_kernel<<<G(E0C), B, 0, stream>>>(ei0 + E0C, cnt0, E0C);
    count_kernel<<<G(E1C), B, 0, stream>>>(ei1 + E1C, cnt1, E1C);
    count_kernel<<<G(E2C), B, 0, stream>>>(ei2 + E2C, cnt2, E2C);
    count_kernel<<<G(N0), B, 0, stream>>>(parent1, pcnt1, N0);
    count_kernel<<<G(N1), B, 0, stream>>>(parent2, pcnt2, N1);
    dis_kernel<<<G(N0), B, 0, stream>>>(cnt0, dis0, N0);
    dis_kernel<<<G(N1), B, 0, stream>>>(cnt1, dis1, N1);
    dis_kernel<<<G(N2), B, 0, stream>>>(cnt2, dis2, N2);
    scan5_kernel<<<5, 1024, 0, stream>>>(
        cnt0, rp0, cur0, N0,
        cnt1, rp1, cur1, N1,
        cnt2, rp2, cur2, N2,
        pcnt1, pp1, pcur1, N1,
        pcnt2, pp2, pcur2, N2);
    fill_edges_kernel<<<G(E0C), B, 0, stream>>>(ei0, ei0 + E0C, cur0, src0, E0C);
    fill_edges_kernel<<<G(E1C), B, 0, stream>>>(ei1, ei1 + E1C, cur1, src1, E1C);
    fill_edges_kernel<<<G(E2C), B, 0, stream>>>(ei2, ei2 + E2C, cur2, src2, E2C);
    fill_parent_kernel<<<G(N0), B, 0, stream>>>(parent1, pcur1, child1, N0);
    fill_parent_kernel<<<G(N1), B, 0, stream>>>(parent2, pcur2, child2, N1);
    bn_pre_kernel<<<2, B, 0, stream>>>(pg, pbeta, pmean, pvar, bnscale, bnshift);

    // ---- gcn0: h0 = relu(gcn(x, ei0, W0, b0)) ----
    mm128_kernel<<<(N0 + 15) / 16, B, 0, stream>>>(
        x, W0, Y, N0, dis0, nullptr, nullptr, nullptr, nullptr, nullptr, 0);
    gather128_kernel<<<G((long long)N0 * 64), B, 0, stream>>>(rp0, src0, Y, dis0, b0, H0, N0);

    // ---- pool1 ----
    gatherP_kernel<<<G((long long)N1 * 64), B, 0, stream>>>(pp1, child1, H0, P, N1);
    mm128_kernel<<<(N1 + 15) / 16, B, 0, stream>>>(
        P, pW, X1, N1, nullptr, nullptr, nullptr, pb, bnscale, bnshift, 1);

    // ---- gcn1 ----
    mm128_kernel<<<(N1 + 15) / 16, B, 0, stream>>>(
        X1, W1, Y, N1, dis1, nullptr, nullptr, nullptr, nullptr, nullptr, 0);
    gather128_kernel<<<G((long long)N1 * 64), B, 0, stream>>>(rp1, src1, Y, dis1, b1, H1, N1);

    // ---- pool2 ----
    gatherP_kernel<<<G((long long)N2 * 64), B, 0, stream>>>(pp2, child2, H1, P, N2);
    mm128_kernel<<<(N2 + 15) / 16, B, 0, stream>>>(
        P, pW + 128 * 128, X2, N2, nullptr, nullptr, nullptr, pb + 128, bnscale + 128, bnshift + 128, 1);

    // ---- gcn2 ----
    mm128_kernel<<<(N2 + 15) / 16, B, 0, stream>>>(
        X2, W2, Y, N2, dis2, nullptr, nullptr, nullptr, nullptr, nullptr, 0);
    gather128_kernel<<<G((long long)N2 * 64), B, 0, stream>>>(rp2, src2, Y, dis2, b2, H2, N2);

    // ---- up level 2: u2 = relu(pool_nn(h2)); v2 = u2 @ W3_top ----
    mm128_kernel<<<(N2 + 15) / 16, B, 0, stream>>>(
        H2, pW + 2 * 128 * 128, U2, N2, nullptr, nullptr, nullptr, pb + 256, bnscale + 256, bnshift + 256, 1);
    mm128_kernel<<<(N2 + 15) / 16, B, 0, stream>>>(
        U2, W3, V2, N2, nullptr, nullptr, nullptr, nullptr, nullptr, nullptr, 0);

    // ---- gcn3: y = dis1 * (v2[parent2] + h1 @ W3_bot); aggregate over ei1 ----
    mm128_kernel<<<(N1 + 15) / 16, B, 0, stream>>>(
        H1, W3 + 128 * 128, Y, N1, dis1, V2, parent2, nullptr, nullptr, nullptr, 0);
    gather128_kernel<<<G((long long)N1 * 64), B, 0, stream>>>(rp1, src1, Y, dis1, b3, HU1, N1);

    // ---- up level 1: u1 = relu(pool_nn(hu1)); w1b = u1 @ W4_top [N1,10] ----
    mm128_kernel<<<(N1 + 15) / 16, B, 0, stream>>>(
        HU1, pW + 3 * 128 * 128, U1, N1, nullptr, nullptr, nullptr, pb + 384, bnscale + 384, bnshift + 384, 1);
    mm10_kernel<<<G(N1), B, 0, stream>>>(U1, W4, W1b, N1, nullptr, nullptr, nullptr);

    // ---- gcn4: y4 = dis0 * (w1b[parent1] + h0 @ W4_bot); gather over ei0 + log_softmax ----
    mm10_kernel<<<G(N0), B, 0, stream>>>(H0, W4 + 128 * 10, Y4, N0, dis0, W1b, parent1);
    gather10_lsm_kernel<<<G(N0), B, 0, stream>>>(rp0, src0, Y4, dis0, b4, out, N0);
}

// Round 6
// 888.996 us; speedup vs baseline: 5.4240x; 1.2819x over previous
//
#include <hip/hip_runtime.h>
#include <math.h>

#define N0 100000
#define N1 20000
#define N2 4000
#define HDIM 128
#define E0C 1600000
#define E1C 320000
#define E2C 64000
#define EPSBN 1e-5f

// concatenated count-array layout
#define OFF0 0
#define OFF1 (N0)
#define OFF2 (N0 + N1)
#define OFF3 (N0 + N1 + N2)
#define OFF4 (N0 + N1 + N2 + N1)
#define OFFT (N0 + N1 + N2 + N1 + N2)       // 148000
#define NBLK ((OFFT + 1023) / 1024)          // 145

// ---------------- CSR build kernels ----------------

__global__ void count_kernel(const int* __restrict__ idx, int* __restrict__ cnt, int n) {
    int i = blockIdx.x * blockDim.x + threadIdx.x;
    if (i < n) atomicAdd(&cnt[idx[i]], 1);
}

// phase 1: per-block (1024 elems) reduce
__global__ __launch_bounds__(256) void scan_k1(const int* __restrict__ c, int* __restrict__ bsum, int n) {
    int t = threadIdx.x;
    int base = blockIdx.x * 1024 + t * 4;
    int s = 0;
    #pragma unroll
    for (int j = 0; j < 4; j++) {
        int idx = base + j;
        if (idx < n) s += c[idx];
    }
    #pragma unroll
    for (int o = 32; o > 0; o >>= 1) s += __shfl_down(s, o, 64);
    __shared__ int ws[4];
    if ((t & 63) == 0) ws[t >> 6] = s;
    __syncthreads();
    if (t == 0) bsum[blockIdx.x] = ws[0] + ws[1] + ws[2] + ws[3];
}

// phase 2: single-block exclusive scan of block sums (nb <= 256)
__global__ __launch_bounds__(256) void scan_k2(int* __restrict__ bsum, int* __restrict__ totalOut, int nb) {
    int t = threadIdx.x;
    int v = (t < nb) ? bsum[t] : 0;
    __shared__ int ts[256];
    ts[t] = v;
    __syncthreads();
    for (int o = 1; o < 256; o <<= 1) {
        int u = (t >= o) ? ts[t - o] : 0;
        __syncthreads();
        ts[t] += u;
        __syncthreads();
    }
    if (t < nb) bsum[t] = ts[t] - v;   // exclusive
    if (t == nb - 1) *totalOut = ts[t];
}

// phase 3: per-block scan (4 contiguous elems/thread) + block offset -> global exclusive scan S[0..n], S[n]=total
__global__ __launch_bounds__(256) void scan_k3(const int* __restrict__ c, const int* __restrict__ bsum,
                                               const int* __restrict__ total,
                                               int* __restrict__ S, int n) {
    int t = threadIdx.x;
    int base = blockIdx.x * 1024 + t * 4;
    int v[4];
    #pragma unroll
    for (int j = 0; j < 4; j++) v[j] = (base + j < n) ? c[base + j] : 0;
    int tsum = v[0] + v[1] + v[2] + v[3];
    __shared__ int ts[256];
    ts[t] = tsum;
    __syncthreads();
    for (int o = 1; o < 256; o <<= 1) {
        int u = (t >= o) ? ts[t - o] : 0;
        __syncthreads();
        ts[t] += u;
        __syncthreads();
    }
    int run = bsum[blockIdx.x] + ts[t] - tsum;
    #pragma unroll
    for (int j = 0; j < 4; j++) {
        if (base + j < n) { S[base + j] = run; run += v[j]; }
    }
    if (blockIdx.x == 0 && t == 0) S[n] = *total;
}

// fixup: split concat scan into per-array rp/cur, fused dis = rsqrt(cnt+1) for the 3 edge arrays
__global__ __launch_bounds__(256) void csr_fixup_kernel(
    const int* __restrict__ S, const int* __restrict__ cntBase,
    int* __restrict__ rp0, int* __restrict__ cur0, float* __restrict__ dis0,
    int* __restrict__ rp1, int* __restrict__ cur1, float* __restrict__ dis1,
    int* __restrict__ rp2, int* __restrict__ cur2, float* __restrict__ dis2,
    int* __restrict__ pp1, int* __restrict__ pcur1,
    int* __restrict__ pp2, int* __restrict__ pcur2)
{
    int g = blockIdx.x * blockDim.x + threadIdx.x;
    if (g >= OFFT) return;
    int s = S[g];
    if (g < OFF1) {
        int i = g;
        int v = s - S[OFF0];
        rp0[i] = v; cur0[i] = v;
        dis0[i] = rsqrtf((float)(cntBase[g] + 1));
        if (i == 0) rp0[N0] = S[OFF1] - S[OFF0];
    } else if (g < OFF2) {
        int i = g - OFF1;
        int v = s - S[OFF1];
        rp1[i] = v; cur1[i] = v;
        dis1[i] = rsqrtf((float)(cntBase[g] + 1));
        if (i == 0) rp1[N1] = S[OFF2] - S[OFF1];
    } else if (g < OFF3) {
        int i = g - OFF2;
        int v = s - S[OFF2];
        rp2[i] = v; cur2[i] = v;
        dis2[i] = rsqrtf((float)(cntBase[g] + 1));
        if (i == 0) rp2[N2] = S[OFF3] - S[OFF2];
    } else if (g < OFF4) {
        int i = g - OFF3;
        int v = s - S[OFF3];
        pp1[i] = v; pcur1[i] = v;
        if (i == 0) pp1[N1] = S[OFF4] - S[OFF3];
    } else {
        int i = g - OFF4;
        int v = s - S[OFF4];
        pp2[i] = v; pcur2[i] = v;
        if (i == 0) pp2[N2] = S[OFFT] - S[OFF4];
    }
}

// srcl[pos] = rows[e], bucketed by cols[e]
__global__ void fill_edges_kernel(const int* __restrict__ rows, const int* __restrict__ cols,
                                  int* __restrict__ cur, int* __restrict__ srcl, int E) {
    int e = blockIdx.x * blockDim.x + threadIdx.x;
    if (e < E) {
        int pos = atomicAdd(&cur[cols[e]], 1);
        srcl[pos] = rows[e];
    }
}

__global__ void fill_parent_kernel(const int* __restrict__ parent,
                                   int* __restrict__ cur, int* __restrict__ childl, int n) {
    int i = blockIdx.x * blockDim.x + threadIdx.x;
    if (i < n) {
        int pos = atomicAdd(&cur[parent[i]], 1);
        childl[pos] = i;
    }
}

// scale = gamma * rsqrt(var+eps); shift = beta - mean*scale
__global__ void bn_pre_kernel(const float* __restrict__ g, const float* __restrict__ beta,
                              const float* __restrict__ mean, const float* __restrict__ var,
                              float* __restrict__ scale, float* __restrict__ shift) {
    int i = blockIdx.x * blockDim.x + threadIdx.x;
    if (i < 4 * HDIM) {
        float s = g[i] * rsqrtf(var[i] + EPSBN);
        scale[i] = s;
        shift[i] = beta[i] - mean[i] * s;
    }
}

// ---------------- gather kernels (no atomics) ----------------

// One wave per destination node. h[c] = relu(dis[c] * (y[c] + sum_{e in CSR[c]} y[src_e]) + bias)
__global__ __launch_bounds__(256) void gather128_kernel(
    const int* __restrict__ rp, const int* __restrict__ srcl,
    const float* __restrict__ y, const float* __restrict__ dis,
    const float* __restrict__ bias, float* __restrict__ h, int n)
{
    int wid = (int)((blockIdx.x * 256 + threadIdx.x) >> 6);  // destination node
    int lane = threadIdx.x & 63;
    if (wid >= n) return;
    const float2* y2 = (const float2*)y;
    float2 acc = y2[(long long)wid * 64 + lane];  // self loop
    int e = rp[wid], e1 = rp[wid + 1];
    for (; e + 1 < e1; e += 2) {
        int s0 = srcl[e], s1 = srcl[e + 1];
        float2 v0 = y2[(long long)s0 * 64 + lane];
        float2 v1 = y2[(long long)s1 * 64 + lane];
        acc.x += v0.x + v1.x;
        acc.y += v0.y + v1.y;
    }
    if (e < e1) {
        int s = srcl[e];
        float2 v = y2[(long long)s * 64 + lane];
        acc.x += v.x; acc.y += v.y;
    }
    float d = dis[wid];
    float2 b = ((const float2*)bias)[lane];
    float2 r;
    r.x = fmaxf(fmaf(d, acc.x, b.x), 0.f);
    r.y = fmaxf(fmaf(d, acc.y, b.y), 0.f);
    ((float2*)h)[(long long)wid * 64 + lane] = r;
}

// Pool segment-sum: p[parent] = sum of h[children]   (one wave per parent)
__global__ __launch_bounds__(256) void gatherP_kernel(
    const int* __restrict__ pp, const int* __restrict__ childl,
    const float* __restrict__ h, float* __restrict__ p, int n)
{
    int wid = (int)((blockIdx.x * 256 + threadIdx.x) >> 6);
    int lane = threadIdx.x & 63;
    if (wid >= n) return;
    const float2* h2 = (const float2*)h;
    float2 acc = make_float2(0.f, 0.f);
    int e = pp[wid], e1 = pp[wid + 1];
    for (; e + 1 < e1; e += 2) {
        int s0 = childl[e], s1 = childl[e + 1];
        float2 v0 = h2[(long long)s0 * 64 + lane];
        float2 v1 = h2[(long long)s1 * 64 + lane];
        acc.x += v0.x + v1.x;
        acc.y += v0.y + v1.y;
    }
    if (e < e1) {
        int s = childl[e];
        float2 v = h2[(long long)s * 64 + lane];
        acc.x += v.x; acc.y += v.y;
    }
    ((float2*)p)[(long long)wid * 64 + lane] = acc;
}

// Final: gather 10-wide + bias + log_softmax, one thread per destination node
__global__ __launch_bounds__(256) void gather10_lsm_kernel(
    const int* __restrict__ rp, const int* __restrict__ srcl,
    const float* __restrict__ y4, const float* __restrict__ dis,
    const float* __restrict__ bias, float* __restrict__ out, int n)
{
    int c = blockIdx.x * blockDim.x + threadIdx.x;
    if (c >= n) return;
    const float2* y2 = (const float2*)y4;  // rows are 5 float2
    float acc[10];
    {
        long long base = (long long)c * 5;
        #pragma unroll
        for (int j = 0; j < 5; j++) {
            float2 v = y2[base + j];
            acc[2 * j] = v.x; acc[2 * j + 1] = v.y;
        }
    }
    int e0 = rp[c], e1 = rp[c + 1];
    for (int e = e0; e < e1; e++) {
        long long base = (long long)srcl[e] * 5;
        #pragma unroll
        for (int j = 0; j < 5; j++) {
            float2 v = y2[base + j];
            acc[2 * j] += v.x; acc[2 * j + 1] += v.y;
        }
    }
    float d = dis[c];
    float m = -1e30f;
    #pragma unroll
    for (int k = 0; k < 10; k++) {
        acc[k] = fmaf(d, acc[k], bias[k]);
        m = fmaxf(m, acc[k]);
    }
    float s = 0.f;
    #pragma unroll
    for (int k = 0; k < 10; k++) s += expf(acc[k] - m);
    float ls = logf(s);
    #pragma unroll
    for (int k = 0; k < 10; k++) out[(long long)c * 10 + k] = acc[k] - m - ls;
}

// ---------------- matmul K=128, N=128 with fused epilogues ----------------
#define MM_ROWS 16
__global__ __launch_bounds__(256) void mm128_kernel(
    const float* __restrict__ A, const float* __restrict__ W,
    float* __restrict__ out, int M,
    const float* __restrict__ dis,
    const float* __restrict__ gsrc, const int* __restrict__ gidx,
    const float* __restrict__ bias,
    const float* __restrict__ bnscale, const float* __restrict__ bnshift,
    int pool)
{
    __shared__ float Ws[64 * 128];   // one K-chunk of W (two chunks streamed)
    __shared__ float As[128 * 20];   // transposed A tile [k][r], 16 rows padded to 20
    int tid = threadIdx.x;

    int rowBase = blockIdx.x * MM_ROWS;
    {
        int k = tid & 127;
        int r0 = tid >> 7;
        #pragma unroll
        for (int i = 0; i < MM_ROWS; i += 2) {
            int r = r0 + i;
            int row = rowBase + r;
            float v = (row < M) ? A[(long long)row * 128 + k] : 0.0f;
            As[k * 20 + r] = v;
        }
    }

    int col = tid & 127;
    int rsub = tid >> 7;
    float acc[8] = {0, 0, 0, 0, 0, 0, 0, 0};

    #pragma unroll
    for (int chunk = 0; chunk < 2; chunk++) {
        __syncthreads();
        const float4* wsrc = (const float4*)(W + chunk * 64 * 128);
        #pragma unroll
        for (int i = 0; i < 8; i++)
            ((float4*)Ws)[tid + i * 256] = wsrc[tid + i * 256];
        __syncthreads();

        int kbase = chunk * 64;
        #pragma unroll 8
        for (int kk = 0; kk < 64; kk++) {
            float w = Ws[kk * 128 + col];
            const float* ap = &As[(kbase + kk) * 20 + rsub * 8];
            float4 a0 = *(const float4*)(ap);
            float4 a1 = *(const float4*)(ap + 4);
            acc[0] += a0.x * w; acc[1] += a0.y * w; acc[2] += a0.z * w; acc[3] += a0.w * w;
            acc[4] += a1.x * w; acc[5] += a1.y * w; acc[6] += a1.z * w; acc[7] += a1.w * w;
        }
    }

    float bcol = 0.f, scol = 0.f, hcol = 0.f;
    if (pool) { bcol = bias[col]; scol = bnscale[col]; hcol = bnshift[col]; }

    #pragma unroll
    for (int i = 0; i < 8; i++) {
        int row = rowBase + rsub * 8 + i;
        if (row >= M) break;
        float v = acc[i];
        if (gsrc) v += gsrc[(long long)gidx[row] * 128 + col];
        if (pool) {
            v = fmaxf(v + bcol, 0.f);
            v = v * scol + hcol;
            v = fmaxf(v, 0.f);
        }
        if (dis) v *= dis[row];
        out[(long long)row * 128 + col] = v;
    }
}

// ---------------- matmul K=128, N=10 (one thread per row) ----------------
__global__ __launch_bounds__(256) void mm10_kernel(
    const float* __restrict__ A, const float* __restrict__ W,  // W [128,10]
    float* __restrict__ out, int M,
    const float* __restrict__ dis,
    const float* __restrict__ gsrc, const int* __restrict__ gidx)
{
    __shared__ float Ws[128 * 10];
    for (int i = threadIdx.x; i < 1280; i += 256) Ws[i] = W[i];
    __syncthreads();
    int row = blockIdx.x * blockDim.x + threadIdx.x;
    if (row >= M) return;
    const float4* a = (const float4*)(A + (long long)row * 128);
    float acc[10] = {0, 0, 0, 0, 0, 0, 0, 0, 0, 0};
    #pragma unroll 4
    for (int k4 = 0; k4 < 32; k4++) {
        float4 av = a[k4];
        int k = k4 * 4;
        #pragma unroll
        for (int c = 0; c < 10; c++) {
            acc[c] += av.x * Ws[(k + 0) * 10 + c] + av.y * Ws[(k + 1) * 10 + c]
                    + av.z * Ws[(k + 2) * 10 + c] + av.w * Ws[(k + 3) * 10 + c];
        }
    }
    float d = dis ? dis[row] : 1.0f;
    const float* g = gsrc ? (gsrc + (long long)gidx[row] * 10) : nullptr;
    #pragma unroll
    for (int c = 0; c < 10; c++) {
        float v = acc[c];
        if (g) v += g[c];
        out[(long long)row * 10 + c] = v * d;
    }
}

// ---------------- launcher ----------------

extern "C" void kernel_launch(void* const* d_in, const int* in_sizes, int n_in,
                              void* d_out, int out_size, void* d_ws, size_t ws_size,
                              hipStream_t stream) {
    const float* x       = (const float*)d_in[0];
    const int*   ei0     = (const int*)d_in[1];
    const int*   ei1     = (const int*)d_in[2];
    const int*   ei2     = (const int*)d_in[3];
    const int*   parent1 = (const int*)d_in[4];
    const int*   parent2 = (const int*)d_in[5];
    const float* W0 = (const float*)d_in[6];
    const float* b0 = (const float*)d_in[7];
    const float* W1 = (const float*)d_in[8];
    const float* b1 = (const float*)d_in[9];
    const float* W2 = (const float*)d_in[10];
    const float* b2 = (const float*)d_in[11];
    const float* W3 = (const float*)d_in[12];
    const float* b3 = (const float*)d_in[13];
    const float* W4 = (const float*)d_in[14];
    const float* b4 = (const float*)d_in[15];
    const float* pW = (const float*)d_in[16];
    const float* pb = (const float*)d_in[17];
    const float* pg = (const float*)d_in[18];
    const float* pbeta = (const float*)d_in[19];
    const float* pmean = (const float*)d_in[20];
    const float* pvar  = (const float*)d_in[21];
    float* out = (float*)d_out;

    char* ws = (char*)d_ws;
    size_t off = 0;
    auto alloc = [&](size_t nbytes) -> char* {
        char* p = ws + off;
        off += ((nbytes + 255) / 256) * 256;
        return p;
    };
    // float buffers
    float* dis0 = (float*)alloc(N0 * 4);
    float* dis1 = (float*)alloc(N1 * 4);
    float* dis2 = (float*)alloc(N2 * 4);
    float* bnscale = (float*)alloc(4 * HDIM * 4);
    float* bnshift = (float*)alloc(4 * HDIM * 4);
    float* Y   = (float*)alloc((size_t)N0 * 128 * 4);
    float* H0  = (float*)alloc((size_t)N0 * 128 * 4);
    float* H1  = (float*)alloc((size_t)N1 * 128 * 4);
    float* P   = (float*)alloc((size_t)N1 * 128 * 4);
    float* X1  = (float*)alloc((size_t)N1 * 128 * 4);
    float* HU1 = (float*)alloc((size_t)N1 * 128 * 4);
    float* U1  = (float*)alloc((size_t)N1 * 128 * 4);
    float* X2  = (float*)alloc((size_t)N2 * 128 * 4);
    float* H2  = (float*)alloc((size_t)N2 * 128 * 4);
    float* U2  = (float*)alloc((size_t)N2 * 128 * 4);
    float* V2  = (float*)alloc((size_t)N2 * 128 * 4);
    float* W1b = (float*)alloc((size_t)N1 * 10 * 4);
    float* Y4  = (float*)alloc((size_t)N0 * 10 * 4);
    // int buffers: counts contiguous (single memset)
    int* cntBase = (int*)alloc((size_t)OFFT * 4);
    int* pcnt1 = cntBase + OFF3;
    int* pcnt2 = cntBase + OFF4;
    int* rp0 = (int*)alloc((N0 + 1) * 4);
    int* rp1 = (int*)alloc((N1 + 1) * 4);
    int* rp2 = (int*)alloc((N2 + 1) * 4);
    int* pp1 = (int*)alloc((N1 + 1) * 4);
    int* pp2 = (int*)alloc((N2 + 1) * 4);
    int* cur0  = (int*)alloc(N0 * 4);
    int* cur1  = (int*)alloc(N1 * 4);
    int* cur2  = (int*)alloc(N2 * 4);
    int* pcur1 = (int*)alloc(N1 * 4);
    int* pcur2 = (int*)alloc(N2 * 4);
    int* src0   = (int*)alloc((size_t)E0C * 4);
    int* src1   = (int*)alloc((size_t)E1C * 4);
    int* src2   = (int*)alloc((size_t)E2C * 4);
    int* child1 = (int*)alloc((size_t)N0 * 4);
    int* child2 = (int*)alloc((size_t)N1 * 4);
    // scan scratch
    int* Sarr   = (int*)alloc((size_t)(OFFT + 1) * 4);
    int* bsum   = (int*)alloc(NBLK * 4);
    int* totalb = (int*)alloc(4);

    const int B = 256;
    auto G = [](long long t) { return (unsigned)((t + 255) / 256); };

    // ---- CSR build ----
    (void)hipMemsetAsync(cntBase, 0, (size_t)OFFT * 4, stream);
    count_kernel<<<G(E0C), B, 0, stream>>>(ei0 + E0C, cntBase + OFF0, E0C);
    count_kernel<<<G(E1C), B, 0, stream>>>(ei1 + E1C, cntBase + OFF1, E1C);
    count_kernel<<<G(E2C), B, 0, stream>>>(ei2 + E2C, cntBase + OFF2, E2C);
    count_kernel<<<G(N0), B, 0, stream>>>(parent1, pcnt1, N0);
    count_kernel<<<G(N1), B, 0, stream>>>(parent2, pcnt2, N1);
    scan_k1<<<NBLK, B, 0, stream>>>(cntBase, bsum, OFFT);
    scan_k2<<<1, B, 0, stream>>>(bsum, totalb, NBLK);
    scan_k3<<<NBLK, B, 0, stream>>>(cntBase, bsum, totalb, Sarr, OFFT);
    csr_fixup_kernel<<<G(OFFT), B, 0, stream>>>(
        Sarr, cntBase,
        rp0, cur0, dis0,
        rp1, cur1, dis1,
        rp2, cur2, dis2,
        pp1, pcur1,
        pp2, pcur2);
    fill_edges_kernel<<<G(E0C), B, 0, stream>>>(ei0, ei0 + E0C, cur0, src0, E0C);
    fill_edges_kernel<<<G(E1C), B, 0, stream>>>(ei1, ei1 + E1C, cur1, src1, E1C);
    fill_edges_kernel<<<G(E2C), B, 0, stream>>>(ei2, ei2 + E2C, cur2, src2, E2C);
    fill_parent_kernel<<<G(N0), B, 0, stream>>>(parent1, pcur1, child1, N0);
    fill_parent_kernel<<<G(N1), B, 0, stream>>>(parent2, pcur2, child2, N1);
    bn_pre_kernel<<<2, B, 0, stream>>>(pg, pbeta, pmean, pvar, bnscale, bnshift);

    // ---- gcn0: h0 = relu(gcn(x, ei0, W0, b0)) ----
    mm128_kernel<<<(N0 + 15) / 16, B, 0, stream>>>(
        x, W0, Y, N0, dis0, nullptr, nullptr, nullptr, nullptr, nullptr, 0);
    gather128_kernel<<<G((long long)N0 * 64), B, 0, stream>>>(rp0, src0, Y, dis0, b0, H0, N0);

    // ---- pool1 ----
    gatherP_kernel<<<G((long long)N1 * 64), B, 0, stream>>>(pp1, child1, H0, P, N1);
    mm128_kernel<<<(N1 + 15) / 16, B, 0, stream>>>(
        P, pW, X1, N1, nullptr, nullptr, nullptr, pb, bnscale, bnshift, 1);

    // ---- gcn1 ----
    mm128_kernel<<<(N1 + 15) / 16, B, 0, stream>>>(
        X1, W1, Y, N1, dis1, nullptr, nullptr, nullptr, nullptr, nullptr, 0);
    gather128_kernel<<<G((long long)N1 * 64), B, 0, stream>>>(rp1, src1, Y, dis1, b1, H1, N1);

    // ---- pool2 ----
    gatherP_kernel<<<G((long long)N2 * 64), B, 0, stream>>>(pp2, child2, H1, P, N2);
    mm128_kernel<<<(N2 + 15) / 16, B, 0, stream>>>(
        P, pW + 128 * 128, X2, N2, nullptr, nullptr, nullptr, pb + 128, bnscale + 128, bnshift + 128, 1);

    // ---- gcn2 ----
    mm128_kernel<<<(N2 + 15) / 16, B, 0, stream>>>(
        X2, W2, Y, N2, dis2, nullptr, nullptr, nullptr, nullptr, nullptr, 0);
    gather128_kernel<<<G((long long)N2 * 64), B, 0, stream>>>(rp2, src2, Y, dis2, b2, H2, N2);

    // ---- up level 2: u2 = relu(pool_nn(h2)); v2 = u2 @ W3_top ----
    mm128_kernel<<<(N2 + 15) / 16, B, 0, stream>>>(
        H2, pW + 2 * 128 * 128, U2, N2, nullptr, nullptr, nullptr, pb + 256, bnscale + 256, bnshift + 256, 1);
    mm128_kernel<<<(N2 + 15) / 16, B, 0, stream>>>(
        U2, W3, V2, N2, nullptr, nullptr, nullptr, nullptr, nullptr, nullptr, 0);

    // ---- gcn3: y = dis1 * (v2[parent2] + h1 @ W3_bot); aggregate over ei1 ----
    mm128_kernel<<<(N1 + 15) / 16, B, 0, stream>>>(
        H1, W3 + 128 * 128, Y, N1, dis1, V2, parent2, nullptr, nullptr, nullptr, 0);
    gather128_kernel<<<G((long long)N1 * 64), B, 0, stream>>>(rp1, src1, Y, dis1, b3, HU1, N1);

    // ---- up level 1: u1 = relu(pool_nn(hu1)); w1b = u1 @ W4_top [N1,10] ----
    mm128_kernel<<<(N1 + 15) / 16, B, 0, stream>>>(
        HU1, pW + 3 * 128 * 128, U1, N1, nullptr, nullptr, nullptr, pb + 384, bnscale + 384, bnshift + 384, 1);
    mm10_kernel<<<G(N1), B, 0, stream>>>(U1, W4, W1b, N1, nullptr, nullptr, nullptr);

    // ---- gcn4: y4 = dis0 * (w1b[parent1] + h0 @ W4_bot); gather over ei0 + log_softmax ----
    mm10_kernel<<<G(N0), B, 0, stream>>>(H0, W4 + 128 * 10, Y4, N0, dis0, W1b, parent1);
    gather10_lsm_kernel<<<G(N0), B, 0, stream>>>(rp0, src0, Y4, dis0, b4, out, N0);
}

// Round 7
// 779.831 us; speedup vs baseline: 6.1833x; 1.1400x over previous
//
#include <hip/hip_runtime.h>
#include <math.h>

#define N0 100000
#define N1 20000
#define N2 4000
#define HDIM 128
#define E0C 1600000
#define E1C 320000
#define E2C 64000
#define EPSBN 1e-5f

// concatenated count-array layout (destination-count arrays)
#define OFF0 0
#define OFF1 (N0)
#define OFF2 (N0 + N1)
#define OFF3 (N0 + N1 + N2)
#define OFF4 (N0 + N1 + N2 + N1)
#define OFFT (N0 + N1 + N2 + N1 + N2)       // 148000
#define NBLK ((OFFT + 1023) / 1024)          // 145

// concatenated work-item layout (edges + parent links)
#define S0 (E0C)                             // 1,600,000
#define S1 (E0C + E1C)                       // 1,920,000
#define S2 (E0C + E1C + E2C)                 // 1,984,000
#define S3 (E0C + E1C + E2C + N0)            // 2,084,000
#define S4 (E0C + E1C + E2C + N0 + N1)       // 2,104,000

// ---------------- CSR build kernels ----------------

// one pass: histogram destination counts AND record each item's within-dest rank
__global__ __launch_bounds__(256) void count_all_kernel(
    const int* __restrict__ ei0c, const int* __restrict__ ei1c, const int* __restrict__ ei2c,
    const int* __restrict__ p1, const int* __restrict__ p2,
    int* __restrict__ cnt, int* __restrict__ rank)
{
    int g = blockIdx.x * blockDim.x + threadIdx.x;
    if (g >= S4) return;
    int x, off;
    if (g < S0)      { x = ei0c[g];      off = OFF0; }
    else if (g < S1) { x = ei1c[g - S0]; off = OFF1; }
    else if (g < S2) { x = ei2c[g - S1]; off = OFF2; }
    else if (g < S3) { x = p1[g - S2];   off = OFF3; }
    else             { x = p2[g - S3];   off = OFF4; }
    rank[g] = atomicAdd(&cnt[off + x], 1);
}

// phase 1: per-block (1024 elems) reduce
__global__ __launch_bounds__(256) void scan_k1(const int* __restrict__ c, int* __restrict__ bsum, int n) {
    int t = threadIdx.x;
    int base = blockIdx.x * 1024 + t * 4;
    int s = 0;
    #pragma unroll
    for (int j = 0; j < 4; j++) {
        int idx = base + j;
        if (idx < n) s += c[idx];
    }
    #pragma unroll
    for (int o = 32; o > 0; o >>= 1) s += __shfl_down(s, o, 64);
    __shared__ int ws[4];
    if ((t & 63) == 0) ws[t >> 6] = s;
    __syncthreads();
    if (t == 0) bsum[blockIdx.x] = ws[0] + ws[1] + ws[2] + ws[3];
}

// phase 2: single-block exclusive scan of block sums (nb <= 256)
__global__ __launch_bounds__(256) void scan_k2(int* __restrict__ bsum, int* __restrict__ totalOut, int nb) {
    int t = threadIdx.x;
    int v = (t < nb) ? bsum[t] : 0;
    __shared__ int ts[256];
    ts[t] = v;
    __syncthreads();
    for (int o = 1; o < 256; o <<= 1) {
        int u = (t >= o) ? ts[t - o] : 0;
        __syncthreads();
        ts[t] += u;
        __syncthreads();
    }
    if (t < nb) bsum[t] = ts[t] - v;   // exclusive
    if (t == nb - 1) *totalOut = ts[t];
}

// phase 3: per-block scan + block offset -> global exclusive scan S[0..n], S[n]=total
__global__ __launch_bounds__(256) void scan_k3(const int* __restrict__ c, const int* __restrict__ bsum,
                                               const int* __restrict__ total,
                                               int* __restrict__ S, int n) {
    int t = threadIdx.x;
    int base = blockIdx.x * 1024 + t * 4;
    int v[4];
    #pragma unroll
    for (int j = 0; j < 4; j++) v[j] = (base + j < n) ? c[base + j] : 0;
    int tsum = v[0] + v[1] + v[2] + v[3];
    __shared__ int ts[256];
    ts[t] = tsum;
    __syncthreads();
    for (int o = 1; o < 256; o <<= 1) {
        int u = (t >= o) ? ts[t - o] : 0;
        __syncthreads();
        ts[t] += u;
        __syncthreads();
    }
    int run = bsum[blockIdx.x] + ts[t] - tsum;
    #pragma unroll
    for (int j = 0; j < 4; j++) {
        if (base + j < n) { S[base + j] = run; run += v[j]; }
    }
    if (blockIdx.x == 0 && t == 0) S[n] = *total;
}

// fixup: split concat scan into per-array rp, fused dis = rsqrt(cnt+1)
__global__ __launch_bounds__(256) void csr_fixup_kernel(
    const int* __restrict__ S, const int* __restrict__ cntBase,
    int* __restrict__ rp0, float* __restrict__ dis0,
    int* __restrict__ rp1, float* __restrict__ dis1,
    int* __restrict__ rp2, float* __restrict__ dis2,
    int* __restrict__ pp1, int* __restrict__ pp2)
{
    int g = blockIdx.x * blockDim.x + threadIdx.x;
    if (g >= OFFT) return;
    int s = S[g];
    if (g < OFF1) {
        int i = g;
        rp0[i] = s - S[OFF0];
        dis0[i] = rsqrtf((float)(cntBase[g] + 1));
        if (i == 0) rp0[N0] = S[OFF1] - S[OFF0];
    } else if (g < OFF2) {
        int i = g - OFF1;
        rp1[i] = s - S[OFF1];
        dis1[i] = rsqrtf((float)(cntBase[g] + 1));
        if (i == 0) rp1[N1] = S[OFF2] - S[OFF1];
    } else if (g < OFF3) {
        int i = g - OFF2;
        rp2[i] = s - S[OFF2];
        dis2[i] = rsqrtf((float)(cntBase[g] + 1));
        if (i == 0) rp2[N2] = S[OFF3] - S[OFF2];
    } else if (g < OFF4) {
        int i = g - OFF3;
        pp1[i] = s - S[OFF3];
        if (i == 0) pp1[N1] = S[OFF4] - S[OFF3];
    } else {
        int i = g - OFF4;
        pp2[i] = s - S[OFF4];
        if (i == 0) pp2[N2] = S[OFFT] - S[OFF4];
    }
}

// atomic-free fill: srcl[rp[dest] + rank] = source   (rank precomputed in count pass)
__global__ __launch_bounds__(256) void fill_all_kernel(
    const int* __restrict__ ei0r, const int* __restrict__ ei0c,
    const int* __restrict__ ei1r, const int* __restrict__ ei1c,
    const int* __restrict__ ei2r, const int* __restrict__ ei2c,
    const int* __restrict__ p1, const int* __restrict__ p2,
    const int* __restrict__ rank,
    const int* __restrict__ rp0, const int* __restrict__ rp1, const int* __restrict__ rp2,
    const int* __restrict__ pp1, const int* __restrict__ pp2,
    int* __restrict__ src0, int* __restrict__ src1, int* __restrict__ src2,
    int* __restrict__ child1, int* __restrict__ child2)
{
    int g = blockIdx.x * blockDim.x + threadIdx.x;
    if (g >= S4) return;
    int r = rank[g];
    if (g < S0) {
        src0[rp0[ei0c[g]] + r] = ei0r[g];
    } else if (g < S1) {
        int i = g - S0;
        src1[rp1[ei1c[i]] + r] = ei1r[i];
    } else if (g < S2) {
        int i = g - S1;
        src2[rp2[ei2c[i]] + r] = ei2r[i];
    } else if (g < S3) {
        int i = g - S2;
        child1[pp1[p1[i]] + r] = i;
    } else {
        int i = g - S3;
        child2[pp2[p2[i]] + r] = i;
    }
}

// scale = gamma * rsqrt(var+eps); shift = beta - mean*scale
__global__ void bn_pre_kernel(const float* __restrict__ g, const float* __restrict__ beta,
                              const float* __restrict__ mean, const float* __restrict__ var,
                              float* __restrict__ scale, float* __restrict__ shift) {
    int i = blockIdx.x * blockDim.x + threadIdx.x;
    if (i < 4 * HDIM) {
        float s = g[i] * rsqrtf(var[i] + EPSBN);
        scale[i] = s;
        shift[i] = beta[i] - mean[i] * s;
    }
}

// ---------------- gather kernels (no atomics) ----------------

// One wave per destination node. h[c] = relu(dis[c] * (y[c] + sum_{e in CSR[c]} y[src_e]) + bias)
__global__ __launch_bounds__(256) void gather128_kernel(
    const int* __restrict__ rp, const int* __restrict__ srcl,
    const float* __restrict__ y, const float* __restrict__ dis,
    const float* __restrict__ bias, float* __restrict__ h, int n)
{
    int wid = (int)((blockIdx.x * 256 + threadIdx.x) >> 6);  // destination node
    int lane = threadIdx.x & 63;
    if (wid >= n) return;
    const float2* y2 = (const float2*)y;
    float2 acc = y2[(long long)wid * 64 + lane];  // self loop
    int e = rp[wid], e1 = rp[wid + 1];
    for (; e + 1 < e1; e += 2) {
        int s0 = srcl[e], s1 = srcl[e + 1];
        float2 v0 = y2[(long long)s0 * 64 + lane];
        float2 v1 = y2[(long long)s1 * 64 + lane];
        acc.x += v0.x + v1.x;
        acc.y += v0.y + v1.y;
    }
    if (e < e1) {
        int s = srcl[e];
        float2 v = y2[(long long)s * 64 + lane];
        acc.x += v.x; acc.y += v.y;
    }
    float d = dis[wid];
    float2 b = ((const float2*)bias)[lane];
    float2 r;
    r.x = fmaxf(fmaf(d, acc.x, b.x), 0.f);
    r.y = fmaxf(fmaf(d, acc.y, b.y), 0.f);
    ((float2*)h)[(long long)wid * 64 + lane] = r;
}

// Pool segment-sum: p[parent] = sum of h[children]   (one wave per parent)
__global__ __launch_bounds__(256) void gatherP_kernel(
    const int* __restrict__ pp, const int* __restrict__ childl,
    const float* __restrict__ h, float* __restrict__ p, int n)
{
    int wid = (int)((blockIdx.x * 256 + threadIdx.x) >> 6);
    int lane = threadIdx.x & 63;
    if (wid >= n) return;
    const float2* h2 = (const float2*)h;
    float2 acc = make_float2(0.f, 0.f);
    int e = pp[wid], e1 = pp[wid + 1];
    for (; e + 1 < e1; e += 2) {
        int s0 = childl[e], s1 = childl[e + 1];
        float2 v0 = h2[(long long)s0 * 64 + lane];
        float2 v1 = h2[(long long)s1 * 64 + lane];
        acc.x += v0.x + v1.x;
        acc.y += v0.y + v1.y;
    }
    if (e < e1) {
        int s = childl[e];
        float2 v = h2[(long long)s * 64 + lane];
        acc.x += v.x; acc.y += v.y;
    }
    ((float2*)p)[(long long)wid * 64 + lane] = acc;
}

// Final: gather 10-wide + bias + log_softmax, one thread per destination, 2-edge ILP unroll
__global__ __launch_bounds__(256) void gather10_lsm_kernel(
    const int* __restrict__ rp, const int* __restrict__ srcl,
    const float* __restrict__ y4, const float* __restrict__ dis,
    const float* __restrict__ bias, float* __restrict__ out, int n)
{
    int c = blockIdx.x * blockDim.x + threadIdx.x;
    if (c >= n) return;
    const float2* y2 = (const float2*)y4;  // rows are 5 float2
    float acc[10];
    {
        long long base = (long long)c * 5;
        #pragma unroll
        for (int j = 0; j < 5; j++) {
            float2 v = y2[base + j];
            acc[2 * j] = v.x; acc[2 * j + 1] = v.y;
        }
    }
    int e = rp[c], e1 = rp[c + 1];
    for (; e + 1 < e1; e += 2) {
        long long bA = (long long)srcl[e] * 5;
        long long bB = (long long)srcl[e + 1] * 5;
        #pragma unroll
        for (int j = 0; j < 5; j++) {
            float2 a = y2[bA + j];
            float2 b = y2[bB + j];
            acc[2 * j] += a.x + b.x;
            acc[2 * j + 1] += a.y + b.y;
        }
    }
    if (e < e1) {
        long long bA = (long long)srcl[e] * 5;
        #pragma unroll
        for (int j = 0; j < 5; j++) {
            float2 a = y2[bA + j];
            acc[2 * j] += a.x;
            acc[2 * j + 1] += a.y;
        }
    }
    float d = dis[c];
    float m = -1e30f;
    #pragma unroll
    for (int k = 0; k < 10; k++) {
        acc[k] = fmaf(d, acc[k], bias[k]);
        m = fmaxf(m, acc[k]);
    }
    float s = 0.f;
    #pragma unroll
    for (int k = 0; k < 10; k++) s += expf(acc[k] - m);
    float ls = logf(s);
    #pragma unroll
    for (int k = 0; k < 10; k++) out[(long long)c * 10 + k] = acc[k] - m - ls;
}

// ---------------- matmul K=128, N=128 with fused epilogues ----------------
#define MM_ROWS 16
__global__ __launch_bounds__(256) void mm128_kernel(
    const float* __restrict__ A, const float* __restrict__ W,
    float* __restrict__ out, int M,
    const float* __restrict__ dis,
    const float* __restrict__ gsrc, const int* __restrict__ gidx,
    const float* __restrict__ bias,
    const float* __restrict__ bnscale, const float* __restrict__ bnshift,
    int pool)
{
    __shared__ float Ws[64 * 128];   // one K-chunk of W (two chunks streamed)
    __shared__ float As[128 * 20];   // transposed A tile [k][r], 16 rows padded to 20
    int tid = threadIdx.x;

    int rowBase = blockIdx.x * MM_ROWS;
    {
        int k = tid & 127;
        int r0 = tid >> 7;
        #pragma unroll
        for (int i = 0; i < MM_ROWS; i += 2) {
            int r = r0 + i;
            int row = rowBase + r;
            float v = (row < M) ? A[(long long)row * 128 + k] : 0.0f;
            As[k * 20 + r] = v;
        }
    }

    int col = tid & 127;
    int rsub = tid >> 7;
    float acc[8] = {0, 0, 0, 0, 0, 0, 0, 0};

    #pragma unroll
    for (int chunk = 0; chunk < 2; chunk++) {
        __syncthreads();
        const float4* wsrc = (const float4*)(W + chunk * 64 * 128);
        #pragma unroll
        for (int i = 0; i < 8; i++)
            ((float4*)Ws)[tid + i * 256] = wsrc[tid + i * 256];
        __syncthreads();

        int kbase = chunk * 64;
        #pragma unroll 8
        for (int kk = 0; kk < 64; kk++) {
            float w = Ws[kk * 128 + col];
            const float* ap = &As[(kbase + kk) * 20 + rsub * 8];
            float4 a0 = *(const float4*)(ap);
            float4 a1 = *(const float4*)(ap + 4);
            acc[0] += a0.x * w; acc[1] += a0.y * w; acc[2] += a0.z * w; acc[3] += a0.w * w;
            acc[4] += a1.x * w; acc[5] += a1.y * w; acc[6] += a1.z * w; acc[7] += a1.w * w;
        }
    }

    float bcol = 0.f, scol = 0.f, hcol = 0.f;
    if (pool) { bcol = bias[col]; scol = bnscale[col]; hcol = bnshift[col]; }

    #pragma unroll
    for (int i = 0; i < 8; i++) {
        int row = rowBase + rsub * 8 + i;
        if (row >= M) break;
        float v = acc[i];
        if (gsrc) v += gsrc[(long long)gidx[row] * 128 + col];
        if (pool) {
            v = fmaxf(v + bcol, 0.f);
            v = v * scol + hcol;
            v = fmaxf(v, 0.f);
        }
        if (dis) v *= dis[row];
        out[(long long)row * 128 + col] = v;
    }
}

// ---------------- matmul K=128, N=10 (one thread per row) ----------------
__global__ __launch_bounds__(256) void mm10_kernel(
    const float* __restrict__ A, const float* __restrict__ W,  // W [128,10]
    float* __restrict__ out, int M,
    const float* __restrict__ dis,
    const float* __restrict__ gsrc, const int* __restrict__ gidx)
{
    __shared__ float Ws[128 * 10];
    for (int i = threadIdx.x; i < 1280; i += 256) Ws[i] = W[i];
    __syncthreads();
    int row = blockIdx.x * blockDim.x + threadIdx.x;
    if (row >= M) return;
    const float4* a = (const float4*)(A + (long long)row * 128);
    float acc[10] = {0, 0, 0, 0, 0, 0, 0, 0, 0, 0};
    #pragma unroll 4
    for (int k4 = 0; k4 < 32; k4++) {
        float4 av = a[k4];
        int k = k4 * 4;
        #pragma unroll
        for (int c = 0; c < 10; c++) {
            acc[c] += av.x * Ws[(k + 0) * 10 + c] + av.y * Ws[(k + 1) * 10 + c]
                    + av.z * Ws[(k + 2) * 10 + c] + av.w * Ws[(k + 3) * 10 + c];
        }
    }
    float d = dis ? dis[row] : 1.0f;
    const float* g = gsrc ? (gsrc + (long long)gidx[row] * 10) : nullptr;
    #pragma unroll
    for (int c = 0; c < 10; c++) {
        float v = acc[c];
        if (g) v += g[c];
        out[(long long)row * 10 + c] = v * d;
    }
}

// ---------------- launcher ----------------

extern "C" void kernel_launch(void* const* d_in, const int* in_sizes, int n_in,
                              void* d_out, int out_size, void* d_ws, size_t ws_size,
                              hipStream_t stream) {
    const float* x       = (const float*)d_in[0];
    const int*   ei0     = (const int*)d_in[1];
    const int*   ei1     = (const int*)d_in[2];
    const int*   ei2     = (const int*)d_in[3];
    const int*   parent1 = (const int*)d_in[4];
    const int*   parent2 = (const int*)d_in[5];
    const float* W0 = (const float*)d_in[6];
    const float* b0 = (const float*)d_in[7];
    const float* W1 = (const float*)d_in[8];
    const float* b1 = (const float*)d_in[9];
    const float* W2 = (const float*)d_in[10];
    const float* b2 = (const float*)d_in[11];
    const float* W3 = (const float*)d_in[12];
    const float* b3 = (const float*)d_in[13];
    const float* W4 = (const float*)d_in[14];
    const float* b4 = (const float*)d_in[15];
    const float* pW = (const float*)d_in[16];
    const float* pb = (const float*)d_in[17];
    const float* pg = (const float*)d_in[18];
    const float* pbeta = (const float*)d_in[19];
    const float* pmean = (const float*)d_in[20];
    const float* pvar  = (const float*)d_in[21];
    float* out = (float*)d_out;

    char* ws = (char*)d_ws;
    size_t off = 0;
    auto alloc = [&](size_t nbytes) -> char* {
        char* p = ws + off;
        off += ((nbytes + 255) / 256) * 256;
        return p;
    };
    // float buffers
    float* dis0 = (float*)alloc(N0 * 4);
    float* dis1 = (float*)alloc(N1 * 4);
    float* dis2 = (float*)alloc(N2 * 4);
    float* bnscale = (float*)alloc(4 * HDIM * 4);
    float* bnshift = (float*)alloc(4 * HDIM * 4);
    float* Y   = (float*)alloc((size_t)N0 * 128 * 4);
    float* H0  = (float*)alloc((size_t)N0 * 128 * 4);
    float* H1  = (float*)alloc((size_t)N1 * 128 * 4);
    float* P   = (float*)alloc((size_t)N1 * 128 * 4);
    float* X1  = (float*)alloc((size_t)N1 * 128 * 4);
    float* HU1 = (float*)alloc((size_t)N1 * 128 * 4);
    float* U1  = (float*)alloc((size_t)N1 * 128 * 4);
    float* X2  = (float*)alloc((size_t)N2 * 128 * 4);
    float* H2  = (float*)alloc((size_t)N2 * 128 * 4);
    float* U2  = (float*)alloc((size_t)N2 * 128 * 4);
    float* V2  = (float*)alloc((size_t)N2 * 128 * 4);
    float* W1b = (float*)alloc((size_t)N1 * 10 * 4);
    float* Y4  = (float*)alloc((size_t)N0 * 10 * 4);
    // int buffers
    int* cntBase = (int*)alloc((size_t)OFFT * 4);
    int* rp0 = (int*)alloc((N0 + 1) * 4);
    int* rp1 = (int*)alloc((N1 + 1) * 4);
    int* rp2 = (int*)alloc((N2 + 1) * 4);
    int* pp1 = (int*)alloc((N1 + 1) * 4);
    int* pp2 = (int*)alloc((N2 + 1) * 4);
    int* rankB = (int*)alloc((size_t)S4 * 4);
    int* src0   = (int*)alloc((size_t)E0C * 4);
    int* src1   = (int*)alloc((size_t)E1C * 4);
    int* src2   = (int*)alloc((size_t)E2C * 4);
    int* child1 = (int*)alloc((size_t)N0 * 4);
    int* child2 = (int*)alloc((size_t)N1 * 4);
    // scan scratch
    int* Sarr   = (int*)alloc((size_t)(OFFT + 1) * 4);
    int* bsum   = (int*)alloc(NBLK * 4);
    int* totalb = (int*)alloc(4);

    const int B = 256;
    auto G = [](long long t) { return (unsigned)((t + 255) / 256); };

    // ---- CSR build ----
    (void)hipMemsetAsync(cntBase, 0, (size_t)OFFT * 4, stream);
    count_all_kernel<<<G(S4), B, 0, stream>>>(
        ei0 + E0C, ei1 + E1C, ei2 + E2C, parent1, parent2, cntBase, rankB);
    scan_k1<<<NBLK, B, 0, stream>>>(cntBase, bsum, OFFT);
    scan_k2<<<1, B, 0, stream>>>(bsum, totalb, NBLK);
    scan_k3<<<NBLK, B, 0, stream>>>(cntBase, bsum, totalb, Sarr, OFFT);
    csr_fixup_kernel<<<G(OFFT), B, 0, stream>>>(
        Sarr, cntBase, rp0, dis0, rp1, dis1, rp2, dis2, pp1, pp2);
    fill_all_kernel<<<G(S4), B, 0, stream>>>(
        ei0, ei0 + E0C, ei1, ei1 + E1C, ei2, ei2 + E2C, parent1, parent2,
        rankB, rp0, rp1, rp2, pp1, pp2,
        src0, src1, src2, child1, child2);
    bn_pre_kernel<<<2, B, 0, stream>>>(pg, pbeta, pmean, pvar, bnscale, bnshift);

    // ---- gcn0: h0 = relu(gcn(x, ei0, W0, b0)) ----
    mm128_kernel<<<(N0 + 15) / 16, B, 0, stream>>>(
        x, W0, Y, N0, dis0, nullptr, nullptr, nullptr, nullptr, nullptr, 0);
    gather128_kernel<<<G((long long)N0 * 64), B, 0, stream>>>(rp0, src0, Y, dis0, b0, H0, N0);

    // ---- pool1 ----
    gatherP_kernel<<<G((long long)N1 * 64), B, 0, stream>>>(pp1, child1, H0, P, N1);
    mm128_kernel<<<(N1 + 15) / 16, B, 0, stream>>>(
        P, pW, X1, N1, nullptr, nullptr, nullptr, pb, bnscale, bnshift, 1);

    // ---- gcn1 ----
    mm128_kernel<<<(N1 + 15) / 16, B, 0, stream>>>(
        X1, W1, Y, N1, dis1, nullptr, nullptr, nullptr, nullptr, nullptr, 0);
    gather128_kernel<<<G((long long)N1 * 64), B, 0, stream>>>(rp1, src1, Y, dis1, b1, H1, N1);

    // ---- pool2 ----
    gatherP_kernel<<<G((long long)N2 * 64), B, 0, stream>>>(pp2, child2, H1, P, N2);
    mm128_kernel<<<(N2 + 15) / 16, B, 0, stream>>>(
        P, pW + 128 * 128, X2, N2, nullptr, nullptr, nullptr, pb + 128, bnscale + 128, bnshift + 128, 1);

    // ---- gcn2 ----
    mm128_kernel<<<(N2 + 15) / 16, B, 0, stream>>>(
        X2, W2, Y, N2, dis2, nullptr, nullptr, nullptr, nullptr, nullptr, 0);
    gather128_kernel<<<G((long long)N2 * 64), B, 0, stream>>>(rp2, src2, Y, dis2, b2, H2, N2);

    // ---- up level 2: u2 = relu(pool_nn(h2)); v2 = u2 @ W3_top ----
    mm128_kernel<<<(N2 + 15) / 16, B, 0, stream>>>(
        H2, pW + 2 * 128 * 128, U2, N2, nullptr, nullptr, nullptr, pb + 256, bnscale + 256, bnshift + 256, 1);
    mm128_kernel<<<(N2 + 15) / 16, B, 0, stream>>>(
        U2, W3, V2, N2, nullptr, nullptr, nullptr, nullptr, nullptr, nullptr, 0);

    // ---- gcn3: y = dis1 * (v2[parent2] + h1 @ W3_bot); aggregate over ei1 ----
    mm128_kernel<<<(N1 + 15) / 16, B, 0, stream>>>(
        H1, W3 + 128 * 128, Y, N1, dis1, V2, parent2, nullptr, nullptr, nullptr, 0);
    gather128_kernel<<<G((long long)N1 * 64), B, 0, stream>>>(rp1, src1, Y, dis1, b3, HU1, N1);

    // ---- up level 1: u1 = relu(pool_nn(hu1)); w1b = u1 @ W4_top [N1,10] ----
    mm128_kernel<<<(N1 + 15) / 16, B, 0, stream>>>(
        HU1, pW + 3 * 128 * 128, U1, N1, nullptr, nullptr, nullptr, pb + 384, bnscale + 384, bnshift + 384, 1);
    mm10_kernel<<<G(N1), B, 0, stream>>>(U1, W4, W1b, N1, nullptr, nullptr, nullptr);

    // ---- gcn4: y4 = dis0 * (w1b[parent1] + h0 @ W4_bot); gather over ei0 + log_softmax ----
    mm10_kernel<<<G(N0), B, 0, stream>>>(H0, W4 + 128 * 10, Y4, N0, dis0, W1b, parent1);
    gather10_lsm_kernel<<<G(N0), B, 0, stream>>>(rp0, src0, Y4, dis0, b4, out, N0);
}

// Round 8
// 692.931 us; speedup vs baseline: 6.9587x; 1.1254x over previous
//
#include <hip/hip_runtime.h>
#include <math.h>

#define N0 100000
#define N1 20000
#define N2 4000
#define HDIM 128
#define E0C 1600000
#define E1C 320000
#define E2C 64000
#define EPSBN 1e-5f

typedef unsigned int u32;

// bf16 pair helpers: low half = feature 2k, high half = feature 2k+1
__device__ __forceinline__ float bl(u32 p) { return __uint_as_float(p << 16); }
__device__ __forceinline__ float bh(u32 p) { return __uint_as_float(p & 0xFFFF0000u); }
__device__ __forceinline__ u32 pack2(float a, float b) {
    u32 ua = __float_as_uint(a), ub = __float_as_uint(b);
    ua = (ua + 0x7FFFu + ((ua >> 16) & 1u)) >> 16;
    ub = (ub + 0x7FFFu + ((ub >> 16) & 1u)) >> 16;
    return ua | (ub << 16);
}

// concatenated count-array layout (destination-count arrays)
#define OFF0 0
#define OFF1 (N0)
#define OFF2 (N0 + N1)
#define OFF3 (N0 + N1 + N2)
#define OFF4 (N0 + N1 + N2 + N1)
#define OFFT (N0 + N1 + N2 + N1 + N2)       // 148000
#define NBLK ((OFFT + 1023) / 1024)          // 145

// concatenated work-item layout (edges + parent links)
#define S0 (E0C)
#define S1 (E0C + E1C)
#define S2 (E0C + E1C + E2C)
#define S3 (E0C + E1C + E2C + N0)
#define S4 (E0C + E1C + E2C + N0 + N1)

// ---------------- CSR build kernels ----------------

__global__ __launch_bounds__(256) void count_all_kernel(
    const int* __restrict__ ei0c, const int* __restrict__ ei1c, const int* __restrict__ ei2c,
    const int* __restrict__ p1, const int* __restrict__ p2,
    int* __restrict__ cnt, int* __restrict__ rank)
{
    int g = blockIdx.x * blockDim.x + threadIdx.x;
    if (g >= S4) return;
    int x, off;
    if (g < S0)      { x = ei0c[g];      off = OFF0; }
    else if (g < S1) { x = ei1c[g - S0]; off = OFF1; }
    else if (g < S2) { x = ei2c[g - S1]; off = OFF2; }
    else if (g < S3) { x = p1[g - S2];   off = OFF3; }
    else             { x = p2[g - S3];   off = OFF4; }
    rank[g] = atomicAdd(&cnt[off + x], 1);
}

__global__ __launch_bounds__(256) void scan_k1(const int* __restrict__ c, int* __restrict__ bsum, int n) {
    int t = threadIdx.x;
    int base = blockIdx.x * 1024 + t * 4;
    int s = 0;
    #pragma unroll
    for (int j = 0; j < 4; j++) {
        int idx = base + j;
        if (idx < n) s += c[idx];
    }
    #pragma unroll
    for (int o = 32; o > 0; o >>= 1) s += __shfl_down(s, o, 64);
    __shared__ int ws[4];
    if ((t & 63) == 0) ws[t >> 6] = s;
    __syncthreads();
    if (t == 0) bsum[blockIdx.x] = ws[0] + ws[1] + ws[2] + ws[3];
}

__global__ __launch_bounds__(256) void scan_k2(int* __restrict__ bsum, int* __restrict__ totalOut, int nb) {
    int t = threadIdx.x;
    int v = (t < nb) ? bsum[t] : 0;
    __shared__ int ts[256];
    ts[t] = v;
    __syncthreads();
    for (int o = 1; o < 256; o <<= 1) {
        int u = (t >= o) ? ts[t - o] : 0;
        __syncthreads();
        ts[t] += u;
        __syncthreads();
    }
    if (t < nb) bsum[t] = ts[t] - v;
    if (t == nb - 1) *totalOut = ts[t];
}

__global__ __launch_bounds__(256) void scan_k3(const int* __restrict__ c, const int* __restrict__ bsum,
                                               const int* __restrict__ total,
                                               int* __restrict__ S, int n) {
    int t = threadIdx.x;
    int base = blockIdx.x * 1024 + t * 4;
    int v[4];
    #pragma unroll
    for (int j = 0; j < 4; j++) v[j] = (base + j < n) ? c[base + j] : 0;
    int tsum = v[0] + v[1] + v[2] + v[3];
    __shared__ int ts[256];
    ts[t] = tsum;
    __syncthreads();
    for (int o = 1; o < 256; o <<= 1) {
        int u = (t >= o) ? ts[t - o] : 0;
        __syncthreads();
        ts[t] += u;
        __syncthreads();
    }
    int run = bsum[blockIdx.x] + ts[t] - tsum;
    #pragma unroll
    for (int j = 0; j < 4; j++) {
        if (base + j < n) { S[base + j] = run; run += v[j]; }
    }
    if (blockIdx.x == 0 && t == 0) S[n] = *total;
}

__global__ __launch_bounds__(256) void csr_fixup_kernel(
    const int* __restrict__ S, const int* __restrict__ cntBase,
    int* __restrict__ rp0, float* __restrict__ dis0,
    int* __restrict__ rp1, float* __restrict__ dis1,
    int* __restrict__ rp2, float* __restrict__ dis2,
    int* __restrict__ pp1, int* __restrict__ pp2)
{
    int g = blockIdx.x * blockDim.x + threadIdx.x;
    if (g >= OFFT) return;
    int s = S[g];
    if (g < OFF1) {
        int i = g;
        rp0[i] = s - S[OFF0];
        dis0[i] = rsqrtf((float)(cntBase[g] + 1));
        if (i == 0) rp0[N0] = S[OFF1] - S[OFF0];
    } else if (g < OFF2) {
        int i = g - OFF1;
        rp1[i] = s - S[OFF1];
        dis1[i] = rsqrtf((float)(cntBase[g] + 1));
        if (i == 0) rp1[N1] = S[OFF2] - S[OFF1];
    } else if (g < OFF3) {
        int i = g - OFF2;
        rp2[i] = s - S[OFF2];
        dis2[i] = rsqrtf((float)(cntBase[g] + 1));
        if (i == 0) rp2[N2] = S[OFF3] - S[OFF2];
    } else if (g < OFF4) {
        int i = g - OFF3;
        pp1[i] = s - S[OFF3];
        if (i == 0) pp1[N1] = S[OFF4] - S[OFF3];
    } else {
        int i = g - OFF4;
        pp2[i] = s - S[OFF4];
        if (i == 0) pp2[N2] = S[OFFT] - S[OFF4];
    }
}

__global__ __launch_bounds__(256) void fill_all_kernel(
    const int* __restrict__ ei0r, const int* __restrict__ ei0c,
    const int* __restrict__ ei1r, const int* __restrict__ ei1c,
    const int* __restrict__ ei2r, const int* __restrict__ ei2c,
    const int* __restrict__ p1, const int* __restrict__ p2,
    const int* __restrict__ rank,
    const int* __restrict__ rp0, const int* __restrict__ rp1, const int* __restrict__ rp2,
    const int* __restrict__ pp1, const int* __restrict__ pp2,
    int* __restrict__ src0, int* __restrict__ src1, int* __restrict__ src2,
    int* __restrict__ child1, int* __restrict__ child2)
{
    int g = blockIdx.x * blockDim.x + threadIdx.x;
    if (g >= S4) return;
    int r = rank[g];
    if (g < S0) {
        src0[rp0[ei0c[g]] + r] = ei0r[g];
    } else if (g < S1) {
        int i = g - S0;
        src1[rp1[ei1c[i]] + r] = ei1r[i];
    } else if (g < S2) {
        int i = g - S1;
        src2[rp2[ei2c[i]] + r] = ei2r[i];
    } else if (g < S3) {
        int i = g - S2;
        child1[pp1[p1[i]] + r] = i;
    } else {
        int i = g - S3;
        child2[pp2[p2[i]] + r] = i;
    }
}

__global__ void bn_pre_kernel(const float* __restrict__ g, const float* __restrict__ beta,
                              const float* __restrict__ mean, const float* __restrict__ var,
                              float* __restrict__ scale, float* __restrict__ shift) {
    int i = blockIdx.x * blockDim.x + threadIdx.x;
    if (i < 4 * HDIM) {
        float s = g[i] * rsqrtf(var[i] + EPSBN);
        scale[i] = s;
        shift[i] = beta[i] - mean[i] * s;
    }
}

// ---------------- gather kernels (bf16 features, fp32 accumulate) ----------------

// One wave per destination. h[c] = relu(dis[c]*(y[c] + sum y[src]) + bias). y,h bf16-packed (64 u32/row).
__global__ __launch_bounds__(256) void gather128_kernel(
    const int* __restrict__ rp, const int* __restrict__ srcl,
    const u32* __restrict__ y, const float* __restrict__ dis,
    const float* __restrict__ bias, u32* __restrict__ h, int n)
{
    int wid = (int)((blockIdx.x * 256 + threadIdx.x) >> 6);
    int lane = threadIdx.x & 63;
    if (wid >= n) return;
    u32 self = y[(long long)wid * 64 + lane];
    float ax = bl(self), ay = bh(self);
    int e = rp[wid], e1 = rp[wid + 1];
    for (; e + 1 < e1; e += 2) {
        int s0 = srcl[e], s1 = srcl[e + 1];
        u32 p0 = y[(long long)s0 * 64 + lane];
        u32 p1 = y[(long long)s1 * 64 + lane];
        ax += bl(p0) + bl(p1);
        ay += bh(p0) + bh(p1);
    }
    if (e < e1) {
        u32 p = y[(long long)srcl[e] * 64 + lane];
        ax += bl(p); ay += bh(p);
    }
    float d = dis[wid];
    float2 b = ((const float2*)bias)[lane];
    float r0 = fmaxf(fmaf(d, ax, b.x), 0.f);
    float r1 = fmaxf(fmaf(d, ay, b.y), 0.f);
    h[(long long)wid * 64 + lane] = pack2(r0, r1);
}

// Pool segment-sum: p[parent] = sum h[children]; bf16 in/out, fp32 accumulate.
__global__ __launch_bounds__(256) void gatherP_kernel(
    const int* __restrict__ pp, const int* __restrict__ childl,
    const u32* __restrict__ h, u32* __restrict__ p, int n)
{
    int wid = (int)((blockIdx.x * 256 + threadIdx.x) >> 6);
    int lane = threadIdx.x & 63;
    if (wid >= n) return;
    float ax = 0.f, ay = 0.f;
    int e = pp[wid], e1 = pp[wid + 1];
    for (; e + 1 < e1; e += 2) {
        int s0 = childl[e], s1 = childl[e + 1];
        u32 p0 = h[(long long)s0 * 64 + lane];
        u32 p1 = h[(long long)s1 * 64 + lane];
        ax += bl(p0) + bl(p1);
        ay += bh(p0) + bh(p1);
    }
    if (e < e1) {
        u32 q = h[(long long)childl[e] * 64 + lane];
        ax += bl(q); ay += bh(q);
    }
    p[(long long)wid * 64 + lane] = pack2(ax, ay);
}

// Final: gather 10-wide fp32 + bias + log_softmax, one thread per destination
__global__ __launch_bounds__(256) void gather10_lsm_kernel(
    const int* __restrict__ rp, const int* __restrict__ srcl,
    const float* __restrict__ y4, const float* __restrict__ dis,
    const float* __restrict__ bias, float* __restrict__ out, int n)
{
    int c = blockIdx.x * blockDim.x + threadIdx.x;
    if (c >= n) return;
    const float2* y2 = (const float2*)y4;
    float acc[10];
    {
        long long base = (long long)c * 5;
        #pragma unroll
        for (int j = 0; j < 5; j++) {
            float2 v = y2[base + j];
            acc[2 * j] = v.x; acc[2 * j + 1] = v.y;
        }
    }
    int e = rp[c], e1 = rp[c + 1];
    for (; e + 1 < e1; e += 2) {
        long long bA = (long long)srcl[e] * 5;
        long long bB = (long long)srcl[e + 1] * 5;
        #pragma unroll
        for (int j = 0; j < 5; j++) {
            float2 a = y2[bA + j];
            float2 b = y2[bB + j];
            acc[2 * j] += a.x + b.x;
            acc[2 * j + 1] += a.y + b.y;
        }
    }
    if (e < e1) {
        long long bA = (long long)srcl[e] * 5;
        #pragma unroll
        for (int j = 0; j < 5; j++) {
            float2 a = y2[bA + j];
            acc[2 * j] += a.x;
            acc[2 * j + 1] += a.y;
        }
    }
    float d = dis[c];
    float m = -1e30f;
    #pragma unroll
    for (int k = 0; k < 10; k++) {
        acc[k] = fmaf(d, acc[k], bias[k]);
        m = fmaxf(m, acc[k]);
    }
    float s = 0.f;
    #pragma unroll
    for (int k = 0; k < 10; k++) s += expf(acc[k] - m);
    float ls = logf(s);
    #pragma unroll
    for (int k = 0; k < 10; k++) out[(long long)c * 10 + k] = acc[k] - m - ls;
}

// ---------------- matmul K=128, N=128; bf16 A in / bf16 out; fp32 W + accumulate ----------------
// Thread owns col pair (2c, 2c+1), rows rsub*4..rsub*4+3.
#define MM_ROWS 16
__global__ __launch_bounds__(256) void mm128_kernel(
    const u32* __restrict__ A, const float* __restrict__ W,
    u32* __restrict__ out, int M,
    const float* __restrict__ dis,
    const u32* __restrict__ gsrc, const int* __restrict__ gidx,
    const float* __restrict__ bias,
    const float* __restrict__ bnscale, const float* __restrict__ bnshift,
    int pool)
{
    __shared__ float Ws[64 * 128];   // one K-chunk of W (two chunks streamed)
    __shared__ float As[128 * 20];   // transposed A tile [k][r], 16 rows padded to 20
    int tid = threadIdx.x;
    int rowBase = blockIdx.x * MM_ROWS;

    // stage A (bf16 -> fp32 transposed): 16 rows * 64 u32 = 1024 u32
    #pragma unroll
    for (int i = 0; i < 4; i++) {
        int flat = tid + i * 256;
        int r = flat >> 6;
        int u = flat & 63;
        int row = rowBase + r;
        u32 p = (row < M) ? A[(long long)row * 64 + u] : 0u;
        As[(2 * u) * 20 + r] = bl(p);
        As[(2 * u + 1) * 20 + r] = bh(p);
    }

    int c = tid & 63;       // col pair: cols 2c, 2c+1
    int rsub = tid >> 6;    // rows rsub*4 .. rsub*4+3
    float acc0[4] = {0, 0, 0, 0};
    float acc1[4] = {0, 0, 0, 0};

    #pragma unroll
    for (int chunk = 0; chunk < 2; chunk++) {
        __syncthreads();
        const float4* wsrc = (const float4*)(W + chunk * 64 * 128);
        #pragma unroll
        for (int i = 0; i < 8; i++)
            ((float4*)Ws)[tid + i * 256] = wsrc[tid + i * 256];
        __syncthreads();

        int kbase = chunk * 64;
        #pragma unroll 8
        for (int kk = 0; kk < 64; kk++) {
            float2 w = *(const float2*)&Ws[kk * 128 + 2 * c];
            float4 a = *(const float4*)&As[(kbase + kk) * 20 + rsub * 4];
            acc0[0] += a.x * w.x; acc1[0] += a.x * w.y;
            acc0[1] += a.y * w.x; acc1[1] += a.y * w.y;
            acc0[2] += a.z * w.x; acc1[2] += a.z * w.y;
            acc0[3] += a.w * w.x; acc1[3] += a.w * w.y;
        }
    }

    float b0 = 0.f, b1 = 0.f, s0 = 0.f, s1 = 0.f, f0 = 0.f, f1 = 0.f;
    if (pool) {
        b0 = bias[2 * c]; b1 = bias[2 * c + 1];
        s0 = bnscale[2 * c]; s1 = bnscale[2 * c + 1];
        f0 = bnshift[2 * c]; f1 = bnshift[2 * c + 1];
    }

    #pragma unroll
    for (int i = 0; i < 4; i++) {
        int row = rowBase + rsub * 4 + i;
        if (row >= M) break;
        float v0 = acc0[i], v1 = acc1[i];
        if (gsrc) {
            u32 p = gsrc[(long long)gidx[row] * 64 + c];
            v0 += bl(p); v1 += bh(p);
        }
        if (pool) {
            v0 = fmaxf(fmaxf(v0 + b0, 0.f) * s0 + f0, 0.f);
            v1 = fmaxf(fmaxf(v1 + b1, 0.f) * s1 + f1, 0.f);
        }
        if (dis) { float d = dis[row]; v0 *= d; v1 *= d; }
        out[(long long)row * 64 + c] = pack2(v0, v1);
    }
}

// ---------------- matmul K=128, N=10; bf16 A, fp32 W/out ----------------
__global__ __launch_bounds__(256) void mm10_kernel(
    const u32* __restrict__ A, const float* __restrict__ W,  // W [128,10]
    float* __restrict__ out, int M,
    const float* __restrict__ dis,
    const float* __restrict__ gsrc, const int* __restrict__ gidx)
{
    __shared__ float Ws[128 * 10];
    for (int i = threadIdx.x; i < 1280; i += 256) Ws[i] = W[i];
    __syncthreads();
    int row = blockIdx.x * blockDim.x + threadIdx.x;
    if (row >= M) return;
    const uint4* a = (const uint4*)(A + (long long)row * 64);
    float acc[10] = {0, 0, 0, 0, 0, 0, 0, 0, 0, 0};
    #pragma unroll 4
    for (int i = 0; i < 16; i++) {
        uint4 av = a[i];
        int k = i * 8;
        float f[8] = { bl(av.x), bh(av.x), bl(av.y), bh(av.y),
                       bl(av.z), bh(av.z), bl(av.w), bh(av.w) };
        #pragma unroll
        for (int j = 0; j < 8; j++) {
            #pragma unroll
            for (int cc = 0; cc < 10; cc++)
                acc[cc] += f[j] * Ws[(k + j) * 10 + cc];
        }
    }
    float d = dis ? dis[row] : 1.0f;
    const float* g = gsrc ? (gsrc + (long long)gidx[row] * 10) : nullptr;
    #pragma unroll
    for (int cc = 0; cc < 10; cc++) {
        float v = acc[cc];
        if (g) v += g[cc];
        out[(long long)row * 10 + cc] = v * d;
    }
}

// ---------------- launcher ----------------

extern "C" void kernel_launch(void* const* d_in, const int* in_sizes, int n_in,
                              void* d_out, int out_size, void* d_ws, size_t ws_size,
                              hipStream_t stream) {
    const float* x       = (const float*)d_in[0];
    const int*   ei0     = (const int*)d_in[1];
    const int*   ei1     = (const int*)d_in[2];
    const int*   ei2     = (const int*)d_in[3];
    const int*   parent1 = (const int*)d_in[4];
    const int*   parent2 = (const int*)d_in[5];
    const float* W0 = (const float*)d_in[6];
    const float* b0 = (const float*)d_in[7];
    const float* W1 = (const float*)d_in[8];
    const float* b1 = (const float*)d_in[9];
    const float* W2 = (const float*)d_in[10];
    const float* b2 = (const float*)d_in[11];
    const float* W3 = (const float*)d_in[12];
    const float* b3 = (const float*)d_in[13];
    const float* W4 = (const float*)d_in[14];
    const float* b4 = (const float*)d_in[15];
    const float* pW = (const float*)d_in[16];
    const float* pb = (const float*)d_in[17];
    const float* pg = (const float*)d_in[18];
    const float* pbeta = (const float*)d_in[19];
    const float* pmean = (const float*)d_in[20];
    const float* pvar  = (const float*)d_in[21];
    float* out = (float*)d_out;

    char* ws = (char*)d_ws;
    size_t off = 0;
    auto alloc = [&](size_t nbytes) -> char* {
        char* p = ws + off;
        off += ((nbytes + 255) / 256) * 256;
        return p;
    };
    // fp32 buffers
    float* dis0 = (float*)alloc(N0 * 4);
    float* dis1 = (float*)alloc(N1 * 4);
    float* dis2 = (float*)alloc(N2 * 4);
    float* bnscale = (float*)alloc(4 * HDIM * 4);
    float* bnshift = (float*)alloc(4 * HDIM * 4);
    float* W1b = (float*)alloc((size_t)N1 * 10 * 4);
    float* Y4  = (float*)alloc((size_t)N0 * 10 * 4);
    // bf16-packed feature buffers (64 u32 per 128-wide row)
    u32* Y   = (u32*)alloc((size_t)N0 * 64 * 4);
    u32* H0  = (u32*)alloc((size_t)N0 * 64 * 4);
    u32* H1  = (u32*)alloc((size_t)N1 * 64 * 4);
    u32* P   = (u32*)alloc((size_t)N1 * 64 * 4);
    u32* X1  = (u32*)alloc((size_t)N1 * 64 * 4);
    u32* HU1 = (u32*)alloc((size_t)N1 * 64 * 4);
    u32* U1  = (u32*)alloc((size_t)N1 * 64 * 4);
    u32* X2  = (u32*)alloc((size_t)N2 * 64 * 4);
    u32* H2  = (u32*)alloc((size_t)N2 * 64 * 4);
    u32* U2  = (u32*)alloc((size_t)N2 * 64 * 4);
    u32* V2  = (u32*)alloc((size_t)N2 * 64 * 4);
    // int buffers
    int* cntBase = (int*)alloc((size_t)OFFT * 4);
    int* rp0 = (int*)alloc((N0 + 1) * 4);
    int* rp1 = (int*)alloc((N1 + 1) * 4);
    int* rp2 = (int*)alloc((N2 + 1) * 4);
    int* pp1 = (int*)alloc((N1 + 1) * 4);
    int* pp2 = (int*)alloc((N2 + 1) * 4);
    int* rankB = (int*)alloc((size_t)S4 * 4);
    int* src0   = (int*)alloc((size_t)E0C * 4);
    int* src1   = (int*)alloc((size_t)E1C * 4);
    int* src2   = (int*)alloc((size_t)E2C * 4);
    int* child1 = (int*)alloc((size_t)N0 * 4);
    int* child2 = (int*)alloc((size_t)N1 * 4);
    // scan scratch
    int* Sarr   = (int*)alloc((size_t)(OFFT + 1) * 4);
    int* bsum   = (int*)alloc(NBLK * 4);
    int* totalb = (int*)alloc(4);

    const int B = 256;
    auto G = [](long long t) { return (unsigned)((t + 255) / 256); };

    // ---- CSR build ----
    (void)hipMemsetAsync(cntBase, 0, (size_t)OFFT * 4, stream);
    count_all_kernel<<<G(S4), B, 0, stream>>>(
        ei0 + E0C, ei1 + E1C, ei2 + E2C, parent1, parent2, cntBase, rankB);
    scan_k1<<<NBLK, B, 0, stream>>>(cntBase, bsum, OFFT);
    scan_k2<<<1, B, 0, stream>>>(bsum, totalb, NBLK);
    scan_k3<<<NBLK, B, 0, stream>>>(cntBase, bsum, totalb, Sarr, OFFT);
    csr_fixup_kernel<<<G(OFFT), B, 0, stream>>>(
        Sarr, cntBase, rp0, dis0, rp1, dis1, rp2, dis2, pp1, pp2);
    fill_all_kernel<<<G(S4), B, 0, stream>>>(
        ei0, ei0 + E0C, ei1, ei1 + E1C, ei2, ei2 + E2C, parent1, parent2,
        rankB, rp0, rp1, rp2, pp1, pp2,
        src0, src1, src2, child1, child2);
    bn_pre_kernel<<<2, B, 0, stream>>>(pg, pbeta, pmean, pvar, bnscale, bnshift);

    // ---- gcn0: x (fp32) must enter as bf16-packed A. Convert via mm128? A=x fp32 — special case:
    // pack x into Y-sized staging first using a tiny conversion inside mm128 is not possible;
    // instead pack x once here (coalesced, 51 MB read / 26 MB write).
    // Reuse U1 buffer? No: size N1. Use a dedicated kernel writing into H0 (overwritten later? H0 needed).
    // We pack into 'rankB'? wrong type/size. Allocate one more buffer:
    // (declared below to keep diff small)
    {
        // pack kernel launched below via lambda-less direct call
    }
    // xb = bf16(x)
    static_assert(sizeof(u32) == 4, "");
    {
        // buffer for packed x
    }
    u32* XB = (u32*)alloc((size_t)N0 * 64 * 4);
    // pack x -> XB
    {
        struct L {};
    }
    // use gatherP-like simple pack kernel:
    extern __global__ void pack_kernel(const float2*, u32*, long long);
    pack_kernel<<<G((long long)N0 * 64), B, 0, stream>>>((const float2*)x, XB, (long long)N0 * 64);

    mm128_kernel<<<(N0 + 15) / 16, B, 0, stream>>>(
        XB, W0, Y, N0, dis0, nullptr, nullptr, nullptr, nullptr, nullptr, 0);
    gather128_kernel<<<G((long long)N0 * 64), B, 0, stream>>>(rp0, src0, Y, dis0, b0, H0, N0);

    // ---- pool1 ----
    gatherP_kernel<<<G((long long)N1 * 64), B, 0, stream>>>(pp1, child1, H0, P, N1);
    mm128_kernel<<<(N1 + 15) / 16, B, 0, stream>>>(
        P, pW, X1, N1, nullptr, nullptr, nullptr, pb, bnscale, bnshift, 1);

    // ---- gcn1 ----
    mm128_kernel<<<(N1 + 15) / 16, B, 0, stream>>>(
        X1, W1, Y, N1, dis1, nullptr, nullptr, nullptr, nullptr, nullptr, 0);
    gather128_kernel<<<G((long long)N1 * 64), B, 0, stream>>>(rp1, src1, Y, dis1, b1, H1, N1);

    // ---- pool2 ----
    gatherP_kernel<<<G((long long)N2 * 64), B, 0, stream>>>(pp2, child2, H1, P, N2);
    mm128_kernel<<<(N2 + 15) / 16, B, 0, stream>>>(
        P, pW + 128 * 128, X2, N2, nullptr, nullptr, nullptr, pb + 128, bnscale + 128, bnshift + 128, 1);

    // ---- gcn2 ----
    mm128_kernel<<<(N2 + 15) / 16, B, 0, stream>>>(
        X2, W2, Y, N2, dis2, nullptr, nullptr, nullptr, nullptr, nullptr, 0);
    gather128_kernel<<<G((long long)N2 * 64), B, 0, stream>>>(rp2, src2, Y, dis2, b2, H2, N2);

    // ---- up level 2 ----
    mm128_kernel<<<(N2 + 15) / 16, B, 0, stream>>>(
        H2, pW + 2 * 128 * 128, U2, N2, nullptr, nullptr, nullptr, pb + 256, bnscale + 256, bnshift + 256, 1);
    mm128_kernel<<<(N2 + 15) / 16, B, 0, stream>>>(
        U2, W3, V2, N2, nullptr, nullptr, nullptr, nullptr, nullptr, nullptr, 0);

    // ---- gcn3 ----
    mm128_kernel<<<(N1 + 15) / 16, B, 0, stream>>>(
        H1, W3 + 128 * 128, Y, N1, dis1, V2, parent2, nullptr, nullptr, nullptr, 0);
    gather128_kernel<<<G((long long)N1 * 64), B, 0, stream>>>(rp1, src1, Y, dis1, b3, HU1, N1);

    // ---- up level 1 ----
    mm128_kernel<<<(N1 + 15) / 16, B, 0, stream>>>(
        HU1, pW + 3 * 128 * 128, U1, N1, nullptr, nullptr, nullptr, pb + 384, bnscale + 384, bnshift + 384, 1);
    mm10_kernel<<<G(N1), B, 0, stream>>>(U1, W4, W1b, N1, nullptr, nullptr, nullptr);

    // ---- gcn4 ----
    mm10_kernel<<<G(N0), B, 0, stream>>>(H0, W4 + 128 * 10, Y4, N0, dis0, W1b, parent1);
    gather10_lsm_kernel<<<G(N0), B, 0, stream>>>(rp0, src0, Y4, dis0, b4, out, N0);
}

// pack fp32 pairs -> bf16-packed u32
__global__ __launch_bounds__(256) void pack_kernel(const float2* __restrict__ src,
                                                   u32* __restrict__ dst, long long n) {
    long long i = (long long)blockIdx.x * blockDim.x + threadIdx.x;
    if (i >= n) return;
    float2 v = src[i];
    dst[i] = pack2(v.x, v.y);
}

// Round 9
// 603.791 us; speedup vs baseline: 7.9860x; 1.1476x over previous
//
#include <hip/hip_runtime.h>
#include <math.h>

#define N0 100000
#define N1 20000
#define N2 4000
#define HDIM 128
#define E0C 1600000
#define E1C 320000
#define E2C 64000
#define EPSBN 1e-5f

typedef unsigned int u32;

// bf16 pair helpers: low half = feature 2k, high half = feature 2k+1
__device__ __forceinline__ float bl(u32 p) { return __uint_as_float(p << 16); }
__device__ __forceinline__ float bh(u32 p) { return __uint_as_float(p & 0xFFFF0000u); }
__device__ __forceinline__ u32 pack2(float a, float b) {
    u32 ua = __float_as_uint(a), ub = __float_as_uint(b);
    ua = (ua + 0x7FFFu + ((ua >> 16) & 1u)) >> 16;
    ub = (ub + 0x7FFFu + ((ub >> 16) & 1u)) >> 16;
    return ua | (ub << 16);
}

// concatenated count-array layout (destination-count arrays)
#define OFF0 0
#define OFF1 (N0)
#define OFF2 (N0 + N1)
#define OFF3 (N0 + N1 + N2)
#define OFF4 (N0 + N1 + N2 + N1)
#define OFFT (N0 + N1 + N2 + N1 + N2)       // 148000
#define NBLK ((OFFT + 1023) / 1024)          // 145

// concatenated work-item layout (edges + parent links)
#define S0 (E0C)
#define S1 (E0C + E1C)
#define S2 (E0C + E1C + E2C)
#define S3 (E0C + E1C + E2C + N0)
#define S4 (E0C + E1C + E2C + N0 + N1)

// ---------------- CSR build kernels ----------------

__global__ __launch_bounds__(256) void count_all_kernel(
    const int* __restrict__ ei0c, const int* __restrict__ ei1c, const int* __restrict__ ei2c,
    const int* __restrict__ p1, const int* __restrict__ p2,
    int* __restrict__ cnt, int* __restrict__ rank)
{
    int g = blockIdx.x * blockDim.x + threadIdx.x;
    if (g >= S4) return;
    int x, off;
    if (g < S0)      { x = ei0c[g];      off = OFF0; }
    else if (g < S1) { x = ei1c[g - S0]; off = OFF1; }
    else if (g < S2) { x = ei2c[g - S1]; off = OFF2; }
    else if (g < S3) { x = p1[g - S2];   off = OFF3; }
    else             { x = p2[g - S3];   off = OFF4; }
    rank[g] = atomicAdd(&cnt[off + x], 1);
}

__global__ __launch_bounds__(256) void scan_k1(const int* __restrict__ c, int* __restrict__ bsum, int n) {
    int t = threadIdx.x;
    int base = blockIdx.x * 1024 + t * 4;
    int s = 0;
    #pragma unroll
    for (int j = 0; j < 4; j++) {
        int idx = base + j;
        if (idx < n) s += c[idx];
    }
    #pragma unroll
    for (int o = 32; o > 0; o >>= 1) s += __shfl_down(s, o, 64);
    __shared__ int ws[4];
    if ((t & 63) == 0) ws[t >> 6] = s;
    __syncthreads();
    if (t == 0) bsum[blockIdx.x] = ws[0] + ws[1] + ws[2] + ws[3];
}

__global__ __launch_bounds__(256) void scan_k2(int* __restrict__ bsum, int* __restrict__ totalOut, int nb) {
    int t = threadIdx.x;
    int v = (t < nb) ? bsum[t] : 0;
    __shared__ int ts[256];
    ts[t] = v;
    __syncthreads();
    for (int o = 1; o < 256; o <<= 1) {
        int u = (t >= o) ? ts[t - o] : 0;
        __syncthreads();
        ts[t] += u;
        __syncthreads();
    }
    if (t < nb) bsum[t] = ts[t] - v;
    if (t == nb - 1) *totalOut = ts[t];
}

__global__ __launch_bounds__(256) void scan_k3(const int* __restrict__ c, const int* __restrict__ bsum,
                                               const int* __restrict__ total,
                                               int* __restrict__ S, int n) {
    int t = threadIdx.x;
    int base = blockIdx.x * 1024 + t * 4;
    int v[4];
    #pragma unroll
    for (int j = 0; j < 4; j++) v[j] = (base + j < n) ? c[base + j] : 0;
    int tsum = v[0] + v[1] + v[2] + v[3];
    __shared__ int ts[256];
    ts[t] = tsum;
    __syncthreads();
    for (int o = 1; o < 256; o <<= 1) {
        int u = (t >= o) ? ts[t - o] : 0;
        __syncthreads();
        ts[t] += u;
        __syncthreads();
    }
    int run = bsum[blockIdx.x] + ts[t] - tsum;
    #pragma unroll
    for (int j = 0; j < 4; j++) {
        if (base + j < n) { S[base + j] = run; run += v[j]; }
    }
    if (blockIdx.x == 0 && t == 0) S[n] = *total;
}

__global__ __launch_bounds__(256) void csr_fixup_kernel(
    const int* __restrict__ S, const int* __restrict__ cntBase,
    int* __restrict__ rp0, float* __restrict__ dis0,
    int* __restrict__ rp1, float* __restrict__ dis1,
    int* __restrict__ rp2, float* __restrict__ dis2,
    int* __restrict__ pp1, int* __restrict__ pp2)
{
    int g = blockIdx.x * blockDim.x + threadIdx.x;
    if (g >= OFFT) return;
    int s = S[g];
    if (g < OFF1) {
        int i = g;
        rp0[i] = s - S[OFF0];
        dis0[i] = rsqrtf((float)(cntBase[g] + 1));
        if (i == 0) rp0[N0] = S[OFF1] - S[OFF0];
    } else if (g < OFF2) {
        int i = g - OFF1;
        rp1[i] = s - S[OFF1];
        dis1[i] = rsqrtf((float)(cntBase[g] + 1));
        if (i == 0) rp1[N1] = S[OFF2] - S[OFF1];
    } else if (g < OFF3) {
        int i = g - OFF2;
        rp2[i] = s - S[OFF2];
        dis2[i] = rsqrtf((float)(cntBase[g] + 1));
        if (i == 0) rp2[N2] = S[OFF3] - S[OFF2];
    } else if (g < OFF4) {
        int i = g - OFF3;
        pp1[i] = s - S[OFF3];
        if (i == 0) pp1[N1] = S[OFF4] - S[OFF3];
    } else {
        int i = g - OFF4;
        pp2[i] = s - S[OFF4];
        if (i == 0) pp2[N2] = S[OFFT] - S[OFF4];
    }
}

__global__ __launch_bounds__(256) void fill_all_kernel(
    const int* __restrict__ ei0r, const int* __restrict__ ei0c,
    const int* __restrict__ ei1r, const int* __restrict__ ei1c,
    const int* __restrict__ ei2r, const int* __restrict__ ei2c,
    const int* __restrict__ p1, const int* __restrict__ p2,
    const int* __restrict__ rank,
    const int* __restrict__ rp0, const int* __restrict__ rp1, const int* __restrict__ rp2,
    const int* __restrict__ pp1, const int* __restrict__ pp2,
    int* __restrict__ src0, int* __restrict__ src1, int* __restrict__ src2,
    int* __restrict__ child1, int* __restrict__ child2)
{
    int g = blockIdx.x * blockDim.x + threadIdx.x;
    if (g >= S4) return;
    int r = rank[g];
    if (g < S0) {
        src0[rp0[ei0c[g]] + r] = ei0r[g];
    } else if (g < S1) {
        int i = g - S0;
        src1[rp1[ei1c[i]] + r] = ei1r[i];
    } else if (g < S2) {
        int i = g - S1;
        src2[rp2[ei2c[i]] + r] = ei2r[i];
    } else if (g < S3) {
        int i = g - S2;
        child1[pp1[p1[i]] + r] = i;
    } else {
        int i = g - S3;
        child2[pp2[p2[i]] + r] = i;
    }
}

__global__ void bn_pre_kernel(const float* __restrict__ g, const float* __restrict__ beta,
                              const float* __restrict__ mean, const float* __restrict__ var,
                              float* __restrict__ scale, float* __restrict__ shift) {
    int i = blockIdx.x * blockDim.x + threadIdx.x;
    if (i < 4 * HDIM) {
        float s = g[i] * rsqrtf(var[i] + EPSBN);
        scale[i] = s;
        shift[i] = beta[i] - mean[i] * s;
    }
}

// ---------------- gather kernels (bf16 features, fp32 accumulate) ----------------

// One wave per destination, 4-edge unroll for MLP.
__global__ __launch_bounds__(256) void gather128_kernel(
    const int* __restrict__ rp, const int* __restrict__ srcl,
    const u32* __restrict__ y, const float* __restrict__ dis,
    const float* __restrict__ bias, u32* __restrict__ h, int n)
{
    int wid = (int)((blockIdx.x * 256 + threadIdx.x) >> 6);
    int lane = threadIdx.x & 63;
    if (wid >= n) return;
    u32 self = y[(long long)wid * 64 + lane];
    float ax = bl(self), ay = bh(self);
    int e = rp[wid], e1 = rp[wid + 1];
    for (; e + 3 < e1; e += 4) {
        int s0 = srcl[e], s1 = srcl[e + 1], s2 = srcl[e + 2], s3 = srcl[e + 3];
        u32 p0 = y[(long long)s0 * 64 + lane];
        u32 p1 = y[(long long)s1 * 64 + lane];
        u32 p2 = y[(long long)s2 * 64 + lane];
        u32 p3 = y[(long long)s3 * 64 + lane];
        ax += (bl(p0) + bl(p1)) + (bl(p2) + bl(p3));
        ay += (bh(p0) + bh(p1)) + (bh(p2) + bh(p3));
    }
    if (e + 1 < e1) {
        u32 p0 = y[(long long)srcl[e] * 64 + lane];
        u32 p1 = y[(long long)srcl[e + 1] * 64 + lane];
        ax += bl(p0) + bl(p1);
        ay += bh(p0) + bh(p1);
        e += 2;
    }
    if (e < e1) {
        u32 p = y[(long long)srcl[e] * 64 + lane];
        ax += bl(p); ay += bh(p);
    }
    float d = dis[wid];
    float2 b = ((const float2*)bias)[lane];
    float r0 = fmaxf(fmaf(d, ax, b.x), 0.f);
    float r1 = fmaxf(fmaf(d, ay, b.y), 0.f);
    h[(long long)wid * 64 + lane] = pack2(r0, r1);
}

// Pool segment-sum with 4-edge unroll
__global__ __launch_bounds__(256) void gatherP_kernel(
    const int* __restrict__ pp, const int* __restrict__ childl,
    const u32* __restrict__ h, u32* __restrict__ p, int n)
{
    int wid = (int)((blockIdx.x * 256 + threadIdx.x) >> 6);
    int lane = threadIdx.x & 63;
    if (wid >= n) return;
    float ax = 0.f, ay = 0.f;
    int e = pp[wid], e1 = pp[wid + 1];
    for (; e + 3 < e1; e += 4) {
        int s0 = childl[e], s1 = childl[e + 1], s2 = childl[e + 2], s3 = childl[e + 3];
        u32 p0 = h[(long long)s0 * 64 + lane];
        u32 p1 = h[(long long)s1 * 64 + lane];
        u32 p2 = h[(long long)s2 * 64 + lane];
        u32 p3 = h[(long long)s3 * 64 + lane];
        ax += (bl(p0) + bl(p1)) + (bl(p2) + bl(p3));
        ay += (bh(p0) + bh(p1)) + (bh(p2) + bh(p3));
    }
    if (e + 1 < e1) {
        u32 p0 = h[(long long)childl[e] * 64 + lane];
        u32 p1 = h[(long long)childl[e + 1] * 64 + lane];
        ax += bl(p0) + bl(p1);
        ay += bh(p0) + bh(p1);
        e += 2;
    }
    if (e < e1) {
        u32 q = h[(long long)childl[e] * 64 + lane];
        ax += bl(q); ay += bh(q);
    }
    p[(long long)wid * 64 + lane] = pack2(ax, ay);
}

// Final: gather bf16-packed 32B rows (5 u32 payload, stride 8) + bias + log_softmax
__global__ __launch_bounds__(256) void gather10_lsm_kernel(
    const int* __restrict__ rp, const int* __restrict__ srcl,
    const u32* __restrict__ y4, const float* __restrict__ dis,
    const float* __restrict__ bias, float* __restrict__ out, int n)
{
    int c = blockIdx.x * blockDim.x + threadIdx.x;
    if (c >= n) return;
    float acc[10];
    {
        long long base = (long long)c * 8;
        uint4 q = *(const uint4*)(y4 + base);
        u32 q4 = y4[base + 4];
        acc[0] = bl(q.x); acc[1] = bh(q.x);
        acc[2] = bl(q.y); acc[3] = bh(q.y);
        acc[4] = bl(q.z); acc[5] = bh(q.z);
        acc[6] = bl(q.w); acc[7] = bh(q.w);
        acc[8] = bl(q4);  acc[9] = bh(q4);
    }
    int e = rp[c], e1 = rp[c + 1];
    for (; e + 1 < e1; e += 2) {
        long long bA = (long long)srcl[e] * 8;
        long long bB = (long long)srcl[e + 1] * 8;
        uint4 qa = *(const uint4*)(y4 + bA);
        u32 qa4 = y4[bA + 4];
        uint4 qb = *(const uint4*)(y4 + bB);
        u32 qb4 = y4[bB + 4];
        acc[0] += bl(qa.x) + bl(qb.x); acc[1] += bh(qa.x) + bh(qb.x);
        acc[2] += bl(qa.y) + bl(qb.y); acc[3] += bh(qa.y) + bh(qb.y);
        acc[4] += bl(qa.z) + bl(qb.z); acc[5] += bh(qa.z) + bh(qb.z);
        acc[6] += bl(qa.w) + bl(qb.w); acc[7] += bh(qa.w) + bh(qb.w);
        acc[8] += bl(qa4) + bl(qb4);   acc[9] += bh(qa4) + bh(qb4);
    }
    if (e < e1) {
        long long bA = (long long)srcl[e] * 8;
        uint4 qa = *(const uint4*)(y4 + bA);
        u32 qa4 = y4[bA + 4];
        acc[0] += bl(qa.x); acc[1] += bh(qa.x);
        acc[2] += bl(qa.y); acc[3] += bh(qa.y);
        acc[4] += bl(qa.z); acc[5] += bh(qa.z);
        acc[6] += bl(qa.w); acc[7] += bh(qa.w);
        acc[8] += bl(qa4);  acc[9] += bh(qa4);
    }
    float d = dis[c];
    float m = -1e30f;
    #pragma unroll
    for (int k = 0; k < 10; k++) {
        acc[k] = fmaf(d, acc[k], bias[k]);
        m = fmaxf(m, acc[k]);
    }
    float s = 0.f;
    #pragma unroll
    for (int k = 0; k < 10; k++) s += expf(acc[k] - m);
    float ls = logf(s);
    #pragma unroll
    for (int k = 0; k < 10; k++) out[(long long)c * 10 + k] = acc[k] - m - ls;
}

// ---------------- matmul K=128, N=128; bf16 (or fp32) A in / bf16 out; fp32 W + accumulate ----------------
#define MM_ROWS 16
__global__ __launch_bounds__(256) void mm128_kernel(
    const void* __restrict__ Av, const float* __restrict__ W,
    u32* __restrict__ out, int M,
    const float* __restrict__ dis,
    const u32* __restrict__ gsrc, const int* __restrict__ gidx,
    const float* __restrict__ bias,
    const float* __restrict__ bnscale, const float* __restrict__ bnshift,
    int pool, int afp32)
{
    __shared__ float Ws[64 * 128];
    __shared__ float As[128 * 20];
    int tid = threadIdx.x;
    int rowBase = blockIdx.x * MM_ROWS;

    if (afp32) {
        const float2* Af = (const float2*)Av;
        #pragma unroll
        for (int i = 0; i < 4; i++) {
            int flat = tid + i * 256;
            int r = flat >> 6;
            int u = flat & 63;
            int row = rowBase + r;
            float2 v = (row < M) ? Af[(long long)row * 64 + u] : make_float2(0.f, 0.f);
            As[(2 * u) * 20 + r] = v.x;
            As[(2 * u + 1) * 20 + r] = v.y;
        }
    } else {
        const u32* Ab = (const u32*)Av;
        #pragma unroll
        for (int i = 0; i < 4; i++) {
            int flat = tid + i * 256;
            int r = flat >> 6;
            int u = flat & 63;
            int row = rowBase + r;
            u32 p = (row < M) ? Ab[(long long)row * 64 + u] : 0u;
            As[(2 * u) * 20 + r] = bl(p);
            As[(2 * u + 1) * 20 + r] = bh(p);
        }
    }

    int c = tid & 63;
    int rsub = tid >> 6;
    float acc0[4] = {0, 0, 0, 0};
    float acc1[4] = {0, 0, 0, 0};

    #pragma unroll
    for (int chunk = 0; chunk < 2; chunk++) {
        __syncthreads();
        const float4* wsrc = (const float4*)(W + chunk * 64 * 128);
        #pragma unroll
        for (int i = 0; i < 8; i++)
            ((float4*)Ws)[tid + i * 256] = wsrc[tid + i * 256];
        __syncthreads();

        int kbase = chunk * 64;
        #pragma unroll 8
        for (int kk = 0; kk < 64; kk++) {
            float2 w = *(const float2*)&Ws[kk * 128 + 2 * c];
            float4 a = *(const float4*)&As[(kbase + kk) * 20 + rsub * 4];
            acc0[0] += a.x * w.x; acc1[0] += a.x * w.y;
            acc0[1] += a.y * w.x; acc1[1] += a.y * w.y;
            acc0[2] += a.z * w.x; acc1[2] += a.z * w.y;
            acc0[3] += a.w * w.x; acc1[3] += a.w * w.y;
        }
    }

    float b0 = 0.f, b1 = 0.f, s0 = 0.f, s1 = 0.f, f0 = 0.f, f1 = 0.f;
    if (pool) {
        b0 = bias[2 * c]; b1 = bias[2 * c + 1];
        s0 = bnscale[2 * c]; s1 = bnscale[2 * c + 1];
        f0 = bnshift[2 * c]; f1 = bnshift[2 * c + 1];
    }

    #pragma unroll
    for (int i = 0; i < 4; i++) {
        int row = rowBase + rsub * 4 + i;
        if (row >= M) break;
        float v0 = acc0[i], v1 = acc1[i];
        if (gsrc) {
            u32 p = gsrc[(long long)gidx[row] * 64 + c];
            v0 += bl(p); v1 += bh(p);
        }
        if (pool) {
            v0 = fmaxf(fmaxf(v0 + b0, 0.f) * s0 + f0, 0.f);
            v1 = fmaxf(fmaxf(v1 + b1, 0.f) * s1 + f1, 0.f);
        }
        if (dis) { float d = dis[row]; v0 *= d; v1 *= d; }
        out[(long long)row * 64 + c] = pack2(v0, v1);
    }
}

// ---------------- matmul K=128, N=10; bf16 A, fp32 W, fp32 out (40B rows) ----------------
__global__ __launch_bounds__(256) void mm10_kernel(
    const u32* __restrict__ A, const float* __restrict__ W,
    float* __restrict__ out, int M)
{
    __shared__ float Ws[128 * 10];
    for (int i = threadIdx.x; i < 1280; i += 256) Ws[i] = W[i];
    __syncthreads();
    int row = blockIdx.x * blockDim.x + threadIdx.x;
    if (row >= M) return;
    const uint4* a = (const uint4*)(A + (long long)row * 64);
    float acc[10] = {0, 0, 0, 0, 0, 0, 0, 0, 0, 0};
    #pragma unroll 4
    for (int i = 0; i < 16; i++) {
        uint4 av = a[i];
        int k = i * 8;
        float f[8] = { bl(av.x), bh(av.x), bl(av.y), bh(av.y),
                       bl(av.z), bh(av.z), bl(av.w), bh(av.w) };
        #pragma unroll
        for (int j = 0; j < 8; j++) {
            #pragma unroll
            for (int cc = 0; cc < 10; cc++)
                acc[cc] += f[j] * Ws[(k + j) * 10 + cc];
        }
    }
    #pragma unroll
    for (int cc = 0; cc < 10; cc++) out[(long long)row * 10 + cc] = acc[cc];
}

// mm10 variant: + gather gsrc fp32 rows, * dis, output bf16-packed stride-8 rows
__global__ __launch_bounds__(256) void mm10p_kernel(
    const u32* __restrict__ A, const float* __restrict__ W,
    u32* __restrict__ outp, int M,
    const float* __restrict__ dis,
    const float* __restrict__ gsrc, const int* __restrict__ gidx)
{
    __shared__ float Ws[128 * 10];
    for (int i = threadIdx.x; i < 1280; i += 256) Ws[i] = W[i];
    __syncthreads();
    int row = blockIdx.x * blockDim.x + threadIdx.x;
    if (row >= M) return;
    const uint4* a = (const uint4*)(A + (long long)row * 64);
    float acc[10] = {0, 0, 0, 0, 0, 0, 0, 0, 0, 0};
    #pragma unroll 4
    for (int i = 0; i < 16; i++) {
        uint4 av = a[i];
        int k = i * 8;
        float f[8] = { bl(av.x), bh(av.x), bl(av.y), bh(av.y),
                       bl(av.z), bh(av.z), bl(av.w), bh(av.w) };
        #pragma unroll
        for (int j = 0; j < 8; j++) {
            #pragma unroll
            for (int cc = 0; cc < 10; cc++)
                acc[cc] += f[j] * Ws[(k + j) * 10 + cc];
        }
    }
    float d = dis[row];
    const float* g = gsrc + (long long)gidx[row] * 10;
    long long base = (long long)row * 8;
    #pragma unroll
    for (int j = 0; j < 5; j++) {
        float v0 = (acc[2 * j] + g[2 * j]) * d;
        float v1 = (acc[2 * j + 1] + g[2 * j + 1]) * d;
        outp[base + j] = pack2(v0, v1);
    }
}

// ---------------- launcher ----------------

extern "C" void kernel_launch(void* const* d_in, const int* in_sizes, int n_in,
                              void* d_out, int out_size, void* d_ws, size_t ws_size,
                              hipStream_t stream) {
    const float* x       = (const float*)d_in[0];
    const int*   ei0     = (const int*)d_in[1];
    const int*   ei1     = (const int*)d_in[2];
    const int*   ei2     = (const int*)d_in[3];
    const int*   parent1 = (const int*)d_in[4];
    const int*   parent2 = (const int*)d_in[5];
    const float* W0 = (const float*)d_in[6];
    const float* b0 = (const float*)d_in[7];
    const float* W1 = (const float*)d_in[8];
    const float* b1 = (const float*)d_in[9];
    const float* W2 = (const float*)d_in[10];
    const float* b2 = (const float*)d_in[11];
    const float* W3 = (const float*)d_in[12];
    const float* b3 = (const float*)d_in[13];
    const float* W4 = (const float*)d_in[14];
    const float* b4 = (const float*)d_in[15];
    const float* pW = (const float*)d_in[16];
    const float* pb = (const float*)d_in[17];
    const float* pg = (const float*)d_in[18];
    const float* pbeta = (const float*)d_in[19];
    const float* pmean = (const float*)d_in[20];
    const float* pvar  = (const float*)d_in[21];
    float* out = (float*)d_out;

    char* ws = (char*)d_ws;
    size_t off = 0;
    auto alloc = [&](size_t nbytes) -> char* {
        char* p = ws + off;
        off += ((nbytes + 255) / 256) * 256;
        return p;
    };
    // fp32 buffers
    float* dis0 = (float*)alloc(N0 * 4);
    float* dis1 = (float*)alloc(N1 * 4);
    float* dis2 = (float*)alloc(N2 * 4);
    float* bnscale = (float*)alloc(4 * HDIM * 4);
    float* bnshift = (float*)alloc(4 * HDIM * 4);
    float* W1b = (float*)alloc((size_t)N1 * 10 * 4);
    // bf16-packed feature buffers (64 u32 per 128-wide row)
    u32* Y   = (u32*)alloc((size_t)N0 * 64 * 4);
    u32* H0  = (u32*)alloc((size_t)N0 * 64 * 4);
    u32* H1  = (u32*)alloc((size_t)N1 * 64 * 4);
    u32* P   = (u32*)alloc((size_t)N1 * 64 * 4);
    u32* X1  = (u32*)alloc((size_t)N1 * 64 * 4);
    u32* HU1 = (u32*)alloc((size_t)N1 * 64 * 4);
    u32* U1  = (u32*)alloc((size_t)N1 * 64 * 4);
    u32* X2  = (u32*)alloc((size_t)N2 * 64 * 4);
    u32* H2  = (u32*)alloc((size_t)N2 * 64 * 4);
    u32* U2  = (u32*)alloc((size_t)N2 * 64 * 4);
    u32* V2  = (u32*)alloc((size_t)N2 * 64 * 4);
    u32* Y4p = (u32*)alloc((size_t)N0 * 8 * 4);   // bf16 stride-8 rows (32 B)
    // int buffers
    int* cntBase = (int*)alloc((size_t)OFFT * 4);
    int* rp0 = (int*)alloc((N0 + 1) * 4);
    int* rp1 = (int*)alloc((N1 + 1) * 4);
    int* rp2 = (int*)alloc((N2 + 1) * 4);
    int* pp1 = (int*)alloc((N1 + 1) * 4);
    int* pp2 = (int*)alloc((N2 + 1) * 4);
    int* rankB = (int*)alloc((size_t)S4 * 4);
    int* src0   = (int*)alloc((size_t)E0C * 4);
    int* src1   = (int*)alloc((size_t)E1C * 4);
    int* src2   = (int*)alloc((size_t)E2C * 4);
    int* child1 = (int*)alloc((size_t)N0 * 4);
    int* child2 = (int*)alloc((size_t)N1 * 4);
    // scan scratch
    int* Sarr   = (int*)alloc((size_t)(OFFT + 1) * 4);
    int* bsum   = (int*)alloc(NBLK * 4);
    int* totalb = (int*)alloc(4);

    const int B = 256;
    auto G = [](long long t) { return (unsigned)((t + 255) / 256); };

    // ---- CSR build ----
    (void)hipMemsetAsync(cntBase, 0, (size_t)OFFT * 4, stream);
    count_all_kernel<<<G(S4), B, 0, stream>>>(
        ei0 + E0C, ei1 + E1C, ei2 + E2C, parent1, parent2, cntBase, rankB);
    scan_k1<<<NBLK, B, 0, stream>>>(cntBase, bsum, OFFT);
    scan_k2<<<1, B, 0, stream>>>(bsum, totalb, NBLK);
    scan_k3<<<NBLK, B, 0, stream>>>(cntBase, bsum, totalb, Sarr, OFFT);
    csr_fixup_kernel<<<G(OFFT), B, 0, stream>>>(
        Sarr, cntBase, rp0, dis0, rp1, dis1, rp2, dis2, pp1, pp2);
    fill_all_kernel<<<G(S4), B, 0, stream>>>(
        ei0, ei0 + E0C, ei1, ei1 + E1C, ei2, ei2 + E2C, parent1, parent2,
        rankB, rp0, rp1, rp2, pp1, pp2,
        src0, src1, src2, child1, child2);
    bn_pre_kernel<<<2, B, 0, stream>>>(pg, pbeta, pmean, pvar, bnscale, bnshift);

    // ---- gcn0: h0 = relu(gcn(x, ei0, W0, b0));  A = fp32 x staged directly ----
    mm128_kernel<<<(N0 + 15) / 16, B, 0, stream>>>(
        x, W0, Y, N0, dis0, nullptr, nullptr, nullptr, nullptr, nullptr, 0, 1);
    gather128_kernel<<<G((long long)N0 * 64), B, 0, stream>>>(rp0, src0, Y, dis0, b0, H0, N0);

    // ---- pool1 ----
    gatherP_kernel<<<G((long long)N1 * 64), B, 0, stream>>>(pp1, child1, H0, P, N1);
    mm128_kernel<<<(N1 + 15) / 16, B, 0, stream>>>(
        P, pW, X1, N1, nullptr, nullptr, nullptr, pb, bnscale, bnshift, 1, 0);

    // ---- gcn1 ----
    mm128_kernel<<<(N1 + 15) / 16, B, 0, stream>>>(
        X1, W1, Y, N1, dis1, nullptr, nullptr, nullptr, nullptr, nullptr, 0, 0);
    gather128_kernel<<<G((long long)N1 * 64), B, 0, stream>>>(rp1, src1, Y, dis1, b1, H1, N1);

    // ---- pool2 ----
    gatherP_kernel<<<G((long long)N2 * 64), B, 0, stream>>>(pp2, child2, H1, P, N2);
    mm128_kernel<<<(N2 + 15) / 16, B, 0, stream>>>(
        P, pW + 128 * 128, X2, N2, nullptr, nullptr, nullptr, pb + 128, bnscale + 128, bnshift + 128, 1, 0);

    // ---- gcn2 ----
    mm128_kernel<<<(N2 + 15) / 16, B, 0, stream>>>(
        X2, W2, Y, N2, dis2, nullptr, nullptr, nullptr, nullptr, nullptr, 0, 0);
    gather128_kernel<<<G((long long)N2 * 64), B, 0, stream>>>(rp2, src2, Y, dis2, b2, H2, N2);

    // ---- up level 2 ----
    mm128_kernel<<<(N2 + 15) / 16, B, 0, stream>>>(
        H2, pW + 2 * 128 * 128, U2, N2, nullptr, nullptr, nullptr, pb + 256, bnscale + 256, bnshift + 256, 1, 0);
    mm128_kernel<<<(N2 + 15) / 16, B, 0, stream>>>(
        U2, W3, V2, N2, nullptr, nullptr, nullptr, nullptr, nullptr, nullptr, 0, 0);

    // ---- gcn3 ----
    mm128_kernel<<<(N1 + 15) / 16, B, 0, stream>>>(
        H1, W3 + 128 * 128, Y, N1, dis1, V2, parent2, nullptr, nullptr, nullptr, 0, 0);
    gather128_kernel<<<G((long long)N1 * 64), B, 0, stream>>>(rp1, src1, Y, dis1, b3, HU1, N1);

    // ---- up level 1 ----
    mm128_kernel<<<(N1 + 15) / 16, B, 0, stream>>>(
        HU1, pW + 3 * 128 * 128, U1, N1, nullptr, nullptr, nullptr, pb + 384, bnscale + 384, bnshift + 384, 1, 0);
    mm10_kernel<<<G(N1), B, 0, stream>>>(U1, W4, W1b, N1);

    // ---- gcn4: y4p = bf16(dis0 * (w1b[parent1] + h0 @ W4_bot)); gather + log_softmax ----
    mm10p_kernel<<<G(N0), B, 0, stream>>>(H0, W4 + 128 * 10, Y4p, N0, dis0, W1b, parent1);
    gather10_lsm_kernel<<<G(N0), B, 0, stream>>>(rp0, src0, Y4p, dis0, b4, out, N0);
}

// Round 10
// 525.448 us; speedup vs baseline: 9.1767x; 1.1491x over previous
//
#include <hip/hip_runtime.h>
#include <math.h>

#define N0 100000
#define N1 20000
#define N2 4000
#define HDIM 128
#define E0C 1600000
#define E1C 320000
#define E2C 64000
#define EPSBN 1e-5f

typedef unsigned int u32;
typedef float f32x4 __attribute__((ext_vector_type(4)));
typedef short bf16x8 __attribute__((ext_vector_type(8)));

union FragU { uint4 u; bf16x8 h; };
__device__ __forceinline__ bf16x8 asbf(uint4 v) { FragU x; x.u = v; return x.h; }

// bf16 pair helpers: low half = feature 2k, high half = feature 2k+1
__device__ __forceinline__ float bl(u32 p) { return __uint_as_float(p << 16); }
__device__ __forceinline__ float bh(u32 p) { return __uint_as_float(p & 0xFFFF0000u); }
__device__ __forceinline__ u32 pack2(float a, float b) {
    u32 ua = __float_as_uint(a), ub = __float_as_uint(b);
    ua = (ua + 0x7FFFu + ((ua >> 16) & 1u)) >> 16;
    ub = (ub + 0x7FFFu + ((ub >> 16) & 1u)) >> 16;
    return ua | (ub << 16);
}

// concatenated count-array layout (destination-count arrays)
#define OFF0 0
#define OFF1 (N0)
#define OFF2 (N0 + N1)
#define OFF3 (N0 + N1 + N2)
#define OFF4 (N0 + N1 + N2 + N1)
#define OFFT (N0 + N1 + N2 + N1 + N2)       // 148000
#define NBLK ((OFFT + 1023) / 1024)          // 145

// concatenated work-item layout (edges + parent links)
#define S0 (E0C)
#define S1 (E0C + E1C)
#define S2 (E0C + E1C + E2C)
#define S3 (E0C + E1C + E2C + N0)
#define S4 (E0C + E1C + E2C + N0 + N1)

// ---------------- CSR build kernels ----------------

__global__ __launch_bounds__(256) void count_all_kernel(
    const int* __restrict__ ei0c, const int* __restrict__ ei1c, const int* __restrict__ ei2c,
    const int* __restrict__ p1, const int* __restrict__ p2,
    int* __restrict__ cnt, int* __restrict__ rank)
{
    int g = blockIdx.x * blockDim.x + threadIdx.x;
    if (g >= S4) return;
    int x, off;
    if (g < S0)      { x = ei0c[g];      off = OFF0; }
    else if (g < S1) { x = ei1c[g - S0]; off = OFF1; }
    else if (g < S2) { x = ei2c[g - S1]; off = OFF2; }
    else if (g < S3) { x = p1[g - S2];   off = OFF3; }
    else             { x = p2[g - S3];   off = OFF4; }
    rank[g] = atomicAdd(&cnt[off + x], 1);
}

__global__ __launch_bounds__(256) void scan_k1(const int* __restrict__ c, int* __restrict__ bsum, int n) {
    int t = threadIdx.x;
    int base = blockIdx.x * 1024 + t * 4;
    int s = 0;
    #pragma unroll
    for (int j = 0; j < 4; j++) {
        int idx = base + j;
        if (idx < n) s += c[idx];
    }
    #pragma unroll
    for (int o = 32; o > 0; o >>= 1) s += __shfl_down(s, o, 64);
    __shared__ int ws[4];
    if ((t & 63) == 0) ws[t >> 6] = s;
    __syncthreads();
    if (t == 0) bsum[blockIdx.x] = ws[0] + ws[1] + ws[2] + ws[3];
}

__global__ __launch_bounds__(256) void scan_k2(int* __restrict__ bsum, int* __restrict__ totalOut, int nb) {
    int t = threadIdx.x;
    int v = (t < nb) ? bsum[t] : 0;
    __shared__ int ts[256];
    ts[t] = v;
    __syncthreads();
    for (int o = 1; o < 256; o <<= 1) {
        int u = (t >= o) ? ts[t - o] : 0;
        __syncthreads();
        ts[t] += u;
        __syncthreads();
    }
    if (t < nb) bsum[t] = ts[t] - v;
    if (t == nb - 1) *totalOut = ts[t];
}

__global__ __launch_bounds__(256) void scan_k3(const int* __restrict__ c, const int* __restrict__ bsum,
                                               const int* __restrict__ total,
                                               int* __restrict__ S, int n) {
    int t = threadIdx.x;
    int base = blockIdx.x * 1024 + t * 4;
    int v[4];
    #pragma unroll
    for (int j = 0; j < 4; j++) v[j] = (base + j < n) ? c[base + j] : 0;
    int tsum = v[0] + v[1] + v[2] + v[3];
    __shared__ int ts[256];
    ts[t] = tsum;
    __syncthreads();
    for (int o = 1; o < 256; o <<= 1) {
        int u = (t >= o) ? ts[t - o] : 0;
        __syncthreads();
        ts[t] += u;
        __syncthreads();
    }
    int run = bsum[blockIdx.x] + ts[t] - tsum;
    #pragma unroll
    for (int j = 0; j < 4; j++) {
        if (base + j < n) { S[base + j] = run; run += v[j]; }
    }
    if (blockIdx.x == 0 && t == 0) S[n] = *total;
}

__global__ __launch_bounds__(256) void csr_fixup_kernel(
    const int* __restrict__ S, const int* __restrict__ cntBase,
    int* __restrict__ rp0, float* __restrict__ dis0,
    int* __restrict__ rp1, float* __restrict__ dis1,
    int* __restrict__ rp2, float* __restrict__ dis2,
    int* __restrict__ pp1, int* __restrict__ pp2)
{
    int g = blockIdx.x * blockDim.x + threadIdx.x;
    if (g >= OFFT) return;
    int s = S[g];
    if (g < OFF1) {
        int i = g;
        rp0[i] = s - S[OFF0];
        dis0[i] = rsqrtf((float)(cntBase[g] + 1));
        if (i == 0) rp0[N0] = S[OFF1] - S[OFF0];
    } else if (g < OFF2) {
        int i = g - OFF1;
        rp1[i] = s - S[OFF1];
        dis1[i] = rsqrtf((float)(cntBase[g] + 1));
        if (i == 0) rp1[N1] = S[OFF2] - S[OFF1];
    } else if (g < OFF3) {
        int i = g - OFF2;
        rp2[i] = s - S[OFF2];
        dis2[i] = rsqrtf((float)(cntBase[g] + 1));
        if (i == 0) rp2[N2] = S[OFF3] - S[OFF2];
    } else if (g < OFF4) {
        int i = g - OFF3;
        pp1[i] = s - S[OFF3];
        if (i == 0) pp1[N1] = S[OFF4] - S[OFF3];
    } else {
        int i = g - OFF4;
        pp2[i] = s - S[OFF4];
        if (i == 0) pp2[N2] = S[OFFT] - S[OFF4];
    }
}

__global__ __launch_bounds__(256) void fill_all_kernel(
    const int* __restrict__ ei0r, const int* __restrict__ ei0c,
    const int* __restrict__ ei1r, const int* __restrict__ ei1c,
    const int* __restrict__ ei2r, const int* __restrict__ ei2c,
    const int* __restrict__ p1, const int* __restrict__ p2,
    const int* __restrict__ rank,
    const int* __restrict__ rp0, const int* __restrict__ rp1, const int* __restrict__ rp2,
    const int* __restrict__ pp1, const int* __restrict__ pp2,
    int* __restrict__ src0, int* __restrict__ src1, int* __restrict__ src2,
    int* __restrict__ child1, int* __restrict__ child2)
{
    int g = blockIdx.x * blockDim.x + threadIdx.x;
    if (g >= S4) return;
    int r = rank[g];
    if (g < S0) {
        src0[rp0[ei0c[g]] + r] = ei0r[g];
    } else if (g < S1) {
        int i = g - S0;
        src1[rp1[ei1c[i]] + r] = ei1r[i];
    } else if (g < S2) {
        int i = g - S1;
        src2[rp2[ei2c[i]] + r] = ei2r[i];
    } else if (g < S3) {
        int i = g - S2;
        child1[pp1[p1[i]] + r] = i;
    } else {
        int i = g - S3;
        child2[pp2[p2[i]] + r] = i;
    }
}

__global__ void bn_pre_kernel(const float* __restrict__ g, const float* __restrict__ beta,
                              const float* __restrict__ mean, const float* __restrict__ var,
                              float* __restrict__ scale, float* __restrict__ shift) {
    int i = blockIdx.x * blockDim.x + threadIdx.x;
    if (i < 4 * HDIM) {
        float s = g[i] * rsqrtf(var[i] + EPSBN);
        scale[i] = s;
        shift[i] = beta[i] - mean[i] * s;
    }
}

// ---------------- gather kernels (bf16 features, fp32 accumulate) ----------------

__global__ __launch_bounds__(256) void gather128_kernel(
    const int* __restrict__ rp, const int* __restrict__ srcl,
    const u32* __restrict__ y, const float* __restrict__ dis,
    const float* __restrict__ bias, u32* __restrict__ h, int n)
{
    int wid = (int)((blockIdx.x * 256 + threadIdx.x) >> 6);
    int lane = threadIdx.x & 63;
    if (wid >= n) return;
    u32 self = y[(long long)wid * 64 + lane];
    float ax = bl(self), ay = bh(self);
    int e = rp[wid], e1 = rp[wid + 1];
    for (; e + 3 < e1; e += 4) {
        int s0 = srcl[e], s1 = srcl[e + 1], s2 = srcl[e + 2], s3 = srcl[e + 3];
        u32 p0 = y[(long long)s0 * 64 + lane];
        u32 p1 = y[(long long)s1 * 64 + lane];
        u32 p2 = y[(long long)s2 * 64 + lane];
        u32 p3 = y[(long long)s3 * 64 + lane];
        ax += (bl(p0) + bl(p1)) + (bl(p2) + bl(p3));
        ay += (bh(p0) + bh(p1)) + (bh(p2) + bh(p3));
    }
    if (e + 1 < e1) {
        u32 p0 = y[(long long)srcl[e] * 64 + lane];
        u32 p1 = y[(long long)srcl[e + 1] * 64 + lane];
        ax += bl(p0) + bl(p1);
        ay += bh(p0) + bh(p1);
        e += 2;
    }
    if (e < e1) {
        u32 p = y[(long long)srcl[e] * 64 + lane];
        ax += bl(p); ay += bh(p);
    }
    float d = dis[wid];
    float2 b = ((const float2*)bias)[lane];
    float r0 = fmaxf(fmaf(d, ax, b.x), 0.f);
    float r1 = fmaxf(fmaf(d, ay, b.y), 0.f);
    h[(long long)wid * 64 + lane] = pack2(r0, r1);
}

__global__ __launch_bounds__(256) void gatherP_kernel(
    const int* __restrict__ pp, const int* __restrict__ childl,
    const u32* __restrict__ h, u32* __restrict__ p, int n)
{
    int wid = (int)((blockIdx.x * 256 + threadIdx.x) >> 6);
    int lane = threadIdx.x & 63;
    if (wid >= n) return;
    float ax = 0.f, ay = 0.f;
    int e = pp[wid], e1 = pp[wid + 1];
    for (; e + 3 < e1; e += 4) {
        int s0 = childl[e], s1 = childl[e + 1], s2 = childl[e + 2], s3 = childl[e + 3];
        u32 p0 = h[(long long)s0 * 64 + lane];
        u32 p1 = h[(long long)s1 * 64 + lane];
        u32 p2 = h[(long long)s2 * 64 + lane];
        u32 p3 = h[(long long)s3 * 64 + lane];
        ax += (bl(p0) + bl(p1)) + (bl(p2) + bl(p3));
        ay += (bh(p0) + bh(p1)) + (bh(p2) + bh(p3));
    }
    if (e + 1 < e1) {
        u32 p0 = h[(long long)childl[e] * 64 + lane];
        u32 p1 = h[(long long)childl[e + 1] * 64 + lane];
        ax += bl(p0) + bl(p1);
        ay += bh(p0) + bh(p1);
        e += 2;
    }
    if (e < e1) {
        u32 q = h[(long long)childl[e] * 64 + lane];
        ax += bl(q); ay += bh(q);
    }
    p[(long long)wid * 64 + lane] = pack2(ax, ay);
}

// Final: gather bf16-packed 32B rows (5 u32 payload, stride 8) + bias + log_softmax
__global__ __launch_bounds__(256) void gather10_lsm_kernel(
    const int* __restrict__ rp, const int* __restrict__ srcl,
    const u32* __restrict__ y4, const float* __restrict__ dis,
    const float* __restrict__ bias, float* __restrict__ out, int n)
{
    int c = blockIdx.x * blockDim.x + threadIdx.x;
    if (c >= n) return;
    float acc[10];
    {
        long long base = (long long)c * 8;
        uint4 q = *(const uint4*)(y4 + base);
        u32 q4 = y4[base + 4];
        acc[0] = bl(q.x); acc[1] = bh(q.x);
        acc[2] = bl(q.y); acc[3] = bh(q.y);
        acc[4] = bl(q.z); acc[5] = bh(q.z);
        acc[6] = bl(q.w); acc[7] = bh(q.w);
        acc[8] = bl(q4);  acc[9] = bh(q4);
    }
    int e = rp[c], e1 = rp[c + 1];
    for (; e + 1 < e1; e += 2) {
        long long bA = (long long)srcl[e] * 8;
        long long bB = (long long)srcl[e + 1] * 8;
        uint4 qa = *(const uint4*)(y4 + bA);
        u32 qa4 = y4[bA + 4];
        uint4 qb = *(const uint4*)(y4 + bB);
        u32 qb4 = y4[bB + 4];
        acc[0] += bl(qa.x) + bl(qb.x); acc[1] += bh(qa.x) + bh(qb.x);
        acc[2] += bl(qa.y) + bl(qb.y); acc[3] += bh(qa.y) + bh(qb.y);
        acc[4] += bl(qa.z) + bl(qb.z); acc[5] += bh(qa.z) + bh(qb.z);
        acc[6] += bl(qa.w) + bl(qb.w); acc[7] += bh(qa.w) + bh(qb.w);
        acc[8] += bl(qa4) + bl(qb4);   acc[9] += bh(qa4) + bh(qb4);
    }
    if (e < e1) {
        long long bA = (long long)srcl[e] * 8;
        uint4 qa = *(const uint4*)(y4 + bA);
        u32 qa4 = y4[bA + 4];
        acc[0] += bl(qa.x); acc[1] += bh(qa.x);
        acc[2] += bl(qa.y); acc[3] += bh(qa.y);
        acc[4] += bl(qa.z); acc[5] += bh(qa.z);
        acc[6] += bl(qa.w); acc[7] += bh(qa.w);
        acc[8] += bl(qa4);  acc[9] += bh(qa4);
    }
    float d = dis[c];
    float m = -1e30f;
    #pragma unroll
    for (int k = 0; k < 10; k++) {
        acc[k] = fmaf(d, acc[k], bias[k]);
        m = fmaxf(m, acc[k]);
    }
    float s = 0.f;
    #pragma unroll
    for (int k = 0; k < 10; k++) s += expf(acc[k] - m);
    float ls = logf(s);
    #pragma unroll
    for (int k = 0; k < 10; k++) out[(long long)c * 10 + k] = acc[k] - m - ls;
}

// ---------------- MFMA matmul K=128, N=128 ----------------
// D = X @ W via mfma_f32_16x16x32_bf16 with W in the A-operand slot, X-rows in B.
// C/D layout (verified): col'=lane&15 (= X row), row'=quad*4+reg (= W col) -> each lane
// holds 4 consecutive output cols of ONE row => direct bf16-pair packing, no shuffle.
// W fragments staged in LDS (bf16-packed, 32 KB, conflict-free b128 reads).
// 64 rows per block (4 waves x 16 rows).
__global__ __launch_bounds__(256) void mm128_kernel(
    const void* __restrict__ Av, const float* __restrict__ W,
    u32* __restrict__ out, int M,
    const float* __restrict__ dis,
    const u32* __restrict__ gsrc, const int* __restrict__ gidx,
    const float* __restrict__ bias,
    const float* __restrict__ bnscale, const float* __restrict__ bnshift,
    int pool, int afp32)
{
    __shared__ u32 WL[8192];   // [t=8][s=4][lane=64][i=4]
    int tid = threadIdx.x;

    // stage W -> bf16 fragments: frag(t,s,lane=(q,m))[j] = W[s*32+q*8+j][t*16+m]
    #pragma unroll
    for (int it = 0; it < 32; it++) {
        int flat = it * 256 + tid;
        int i = flat & 3;
        int ln = (flat >> 2) & 63;
        int s = (flat >> 8) & 3;
        int t = flat >> 10;
        int mm = ln & 15, qq = ln >> 4;
        int k0 = s * 32 + qq * 8 + 2 * i;
        int col = t * 16 + mm;
        WL[flat] = pack2(W[k0 * 128 + col], W[(k0 + 1) * 128 + col]);
    }
    __syncthreads();

    int lane = tid & 63;
    int w = tid >> 6;
    int m = lane & 15, q = lane >> 4;
    int row = blockIdx.x * 64 + w * 16 + m;
    bool live = (row < M);

    // B-operand fragments: X[row][k = s*32 + q*8 + j]
    uint4 xb[4];
    if (live) {
        if (afp32) {
            const float* Af = (const float*)Av;
            #pragma unroll
            for (int s = 0; s < 4; s++) {
                const float4* p = (const float4*)(Af + (long long)row * 128 + s * 32 + q * 8);
                float4 f0 = p[0], f1 = p[1];
                xb[s].x = pack2(f0.x, f0.y);
                xb[s].y = pack2(f0.z, f0.w);
                xb[s].z = pack2(f1.x, f1.y);
                xb[s].w = pack2(f1.z, f1.w);
            }
        } else {
            const u32* Ab = (const u32*)Av;
            #pragma unroll
            for (int s = 0; s < 4; s++)
                xb[s] = *(const uint4*)(Ab + (long long)row * 64 + s * 16 + q * 4);
        }
    } else {
        xb[0] = xb[1] = xb[2] = xb[3] = make_uint4(0u, 0u, 0u, 0u);
    }

    float d = 1.0f;
    if (dis && live) d = dis[row];
    long long gbase = (gsrc && live) ? (long long)gidx[row] * 64 : 0;

    #pragma unroll
    for (int t = 0; t < 8; t++) {
        f32x4 acc = {0.f, 0.f, 0.f, 0.f};
        #pragma unroll
        for (int s = 0; s < 4; s++) {
            uint4 wa = *(const uint4*)&WL[((t * 4 + s) * 64 + lane) * 4];
            acc = __builtin_amdgcn_mfma_f32_16x16x32_bf16(asbf(wa), asbf(xb[s]), acc, 0, 0, 0);
        }
        if (live) {
            float v0 = acc[0], v1 = acc[1], v2 = acc[2], v3 = acc[3];
            int cbase = t * 16 + q * 4;
            if (gsrc) {
                uint2 g = *(const uint2*)(gsrc + gbase + (cbase >> 1));
                v0 += bl(g.x); v1 += bh(g.x);
                v2 += bl(g.y); v3 += bh(g.y);
            }
            if (pool) {
                float4 bb = *(const float4*)(bias + cbase);
                float4 sc = *(const float4*)(bnscale + cbase);
                float4 sh = *(const float4*)(bnshift + cbase);
                v0 = fmaxf(fmaxf(v0 + bb.x, 0.f) * sc.x + sh.x, 0.f);
                v1 = fmaxf(fmaxf(v1 + bb.y, 0.f) * sc.y + sh.y, 0.f);
                v2 = fmaxf(fmaxf(v2 + bb.z, 0.f) * sc.z + sh.z, 0.f);
                v3 = fmaxf(fmaxf(v3 + bb.w, 0.f) * sc.w + sh.w, 0.f);
            }
            v0 *= d; v1 *= d; v2 *= d; v3 *= d;
            uint2 st;
            st.x = pack2(v0, v1);
            st.y = pack2(v2, v3);
            *(uint2*)(out + (long long)row * 64 + (cbase >> 1)) = st;
        }
    }
}

// ---------------- matmul K=128, N=10; bf16 A, fp32 W, fp32 out ----------------
__global__ __launch_bounds__(256) void mm10_kernel(
    const u32* __restrict__ A, const float* __restrict__ W,
    float* __restrict__ out, int M)
{
    __shared__ float Ws[128 * 10];
    for (int i = threadIdx.x; i < 1280; i += 256) Ws[i] = W[i];
    __syncthreads();
    int row = blockIdx.x * blockDim.x + threadIdx.x;
    if (row >= M) return;
    const uint4* a = (const uint4*)(A + (long long)row * 64);
    float acc[10] = {0, 0, 0, 0, 0, 0, 0, 0, 0, 0};
    #pragma unroll 4
    for (int i = 0; i < 16; i++) {
        uint4 av = a[i];
        int k = i * 8;
        float f[8] = { bl(av.x), bh(av.x), bl(av.y), bh(av.y),
                       bl(av.z), bh(av.z), bl(av.w), bh(av.w) };
        #pragma unroll
        for (int j = 0; j < 8; j++) {
            #pragma unroll
            for (int cc = 0; cc < 10; cc++)
                acc[cc] += f[j] * Ws[(k + j) * 10 + cc];
        }
    }
    #pragma unroll
    for (int cc = 0; cc < 10; cc++) out[(long long)row * 10 + cc] = acc[cc];
}

// mm10 variant: + gather gsrc fp32 rows, * dis, output bf16-packed stride-8 rows
__global__ __launch_bounds__(256) void mm10p_kernel(
    const u32* __restrict__ A, const float* __restrict__ W,
    u32* __restrict__ outp, int M,
    const float* __restrict__ dis,
    const float* __restrict__ gsrc, const int* __restrict__ gidx)
{
    __shared__ float Ws[128 * 10];
    for (int i = threadIdx.x; i < 1280; i += 256) Ws[i] = W[i];
    __syncthreads();
    int row = blockIdx.x * blockDim.x + threadIdx.x;
    if (row >= M) return;
    const uint4* a = (const uint4*)(A + (long long)row * 64);
    float acc[10] = {0, 0, 0, 0, 0, 0, 0, 0, 0, 0};
    #pragma unroll 4
    for (int i = 0; i < 16; i++) {
        uint4 av = a[i];
        int k = i * 8;
        float f[8] = { bl(av.x), bh(av.x), bl(av.y), bh(av.y),
                       bl(av.z), bh(av.z), bl(av.w), bh(av.w) };
        #pragma unroll
        for (int j = 0; j < 8; j++) {
            #pragma unroll
            for (int cc = 0; cc < 10; cc++)
                acc[cc] += f[j] * Ws[(k + j) * 10 + cc];
        }
    }
    float d = dis[row];
    const float* g = gsrc + (long long)gidx[row] * 10;
    long long base = (long long)row * 8;
    #pragma unroll
    for (int j = 0; j < 5; j++) {
        float v0 = (acc[2 * j] + g[2 * j]) * d;
        float v1 = (acc[2 * j + 1] + g[2 * j + 1]) * d;
        outp[base + j] = pack2(v0, v1);
    }
}

// ---------------- launcher ----------------

extern "C" void kernel_launch(void* const* d_in, const int* in_sizes, int n_in,
                              void* d_out, int out_size, void* d_ws, size_t ws_size,
                              hipStream_t stream) {
    const float* x       = (const float*)d_in[0];
    const int*   ei0     = (const int*)d_in[1];
    const int*   ei1     = (const int*)d_in[2];
    const int*   ei2     = (const int*)d_in[3];
    const int*   parent1 = (const int*)d_in[4];
    const int*   parent2 = (const int*)d_in[5];
    const float* W0 = (const float*)d_in[6];
    const float* b0 = (const float*)d_in[7];
    const float* W1 = (const float*)d_in[8];
    const float* b1 = (const float*)d_in[9];
    const float* W2 = (const float*)d_in[10];
    const float* b2 = (const float*)d_in[11];
    const float* W3 = (const float*)d_in[12];
    const float* b3 = (const float*)d_in[13];
    const float* W4 = (const float*)d_in[14];
    const float* b4 = (const float*)d_in[15];
    const float* pW = (const float*)d_in[16];
    const float* pb = (const float*)d_in[17];
    const float* pg = (const float*)d_in[18];
    const float* pbeta = (const float*)d_in[19];
    const float* pmean = (const float*)d_in[20];
    const float* pvar  = (const float*)d_in[21];
    float* out = (float*)d_out;

    char* ws = (char*)d_ws;
    size_t off = 0;
    auto alloc = [&](size_t nbytes) -> char* {
        char* p = ws + off;
        off += ((nbytes + 255) / 256) * 256;
        return p;
    };
    // fp32 buffers
    float* dis0 = (float*)alloc(N0 * 4);
    float* dis1 = (float*)alloc(N1 * 4);
    float* dis2 = (float*)alloc(N2 * 4);
    float* bnscale = (float*)alloc(4 * HDIM * 4);
    float* bnshift = (float*)alloc(4 * HDIM * 4);
    float* W1b = (float*)alloc((size_t)N1 * 10 * 4);
    // bf16-packed feature buffers (64 u32 per 128-wide row)
    u32* Y   = (u32*)alloc((size_t)N0 * 64 * 4);
    u32* H0  = (u32*)alloc((size_t)N0 * 64 * 4);
    u32* H1  = (u32*)alloc((size_t)N1 * 64 * 4);
    u32* P   = (u32*)alloc((size_t)N1 * 64 * 4);
    u32* X1  = (u32*)alloc((size_t)N1 * 64 * 4);
    u32* HU1 = (u32*)alloc((size_t)N1 * 64 * 4);
    u32* U1  = (u32*)alloc((size_t)N1 * 64 * 4);
    u32* X2  = (u32*)alloc((size_t)N2 * 64 * 4);
    u32* H2  = (u32*)alloc((size_t)N2 * 64 * 4);
    u32* U2  = (u32*)alloc((size_t)N2 * 64 * 4);
    u32* V2  = (u32*)alloc((size_t)N2 * 64 * 4);
    u32* Y4p = (u32*)alloc((size_t)N0 * 8 * 4);   // bf16 stride-8 rows (32 B)
    // int buffers
    int* cntBase = (int*)alloc((size_t)OFFT * 4);
    int* rp0 = (int*)alloc((N0 + 1) * 4);
    int* rp1 = (int*)alloc((N1 + 1) * 4);
    int* rp2 = (int*)alloc((N2 + 1) * 4);
    int* pp1 = (int*)alloc((N1 + 1) * 4);
    int* pp2 = (int*)alloc((N2 + 1) * 4);
    int* rankB = (int*)alloc((size_t)S4 * 4);
    int* src0   = (int*)alloc((size_t)E0C * 4);
    int* src1   = (int*)alloc((size_t)E1C * 4);
    int* src2   = (int*)alloc((size_t)E2C * 4);
    int* child1 = (int*)alloc((size_t)N0 * 4);
    int* child2 = (int*)alloc((size_t)N1 * 4);
    // scan scratch
    int* Sarr   = (int*)alloc((size_t)(OFFT + 1) * 4);
    int* bsum   = (int*)alloc(NBLK * 4);
    int* totalb = (int*)alloc(4);

    const int B = 256;
    auto G = [](long long t) { return (unsigned)((t + 255) / 256); };
    auto G64 = [](long long m) { return (unsigned)((m + 63) / 64); };

    // ---- CSR build ----
    (void)hipMemsetAsync(cntBase, 0, (size_t)OFFT * 4, stream);
    count_all_kernel<<<G(S4), B, 0, stream>>>(
        ei0 + E0C, ei1 + E1C, ei2 + E2C, parent1, parent2, cntBase, rankB);
    scan_k1<<<NBLK, B, 0, stream>>>(cntBase, bsum, OFFT);
    scan_k2<<<1, B, 0, stream>>>(bsum, totalb, NBLK);
    scan_k3<<<NBLK, B, 0, stream>>>(cntBase, bsum, totalb, Sarr, OFFT);
    csr_fixup_kernel<<<G(OFFT), B, 0, stream>>>(
        Sarr, cntBase, rp0, dis0, rp1, dis1, rp2, dis2, pp1, pp2);
    fill_all_kernel<<<G(S4), B, 0, stream>>>(
        ei0, ei0 + E0C, ei1, ei1 + E1C, ei2, ei2 + E2C, parent1, parent2,
        rankB, rp0, rp1, rp2, pp1, pp2,
        src0, src1, src2, child1, child2);
    bn_pre_kernel<<<2, B, 0, stream>>>(pg, pbeta, pmean, pvar, bnscale, bnshift);

    // ---- gcn0: h0 = relu(gcn(x, ei0, W0, b0));  A = fp32 x staged directly ----
    mm128_kernel<<<G64(N0), B, 0, stream>>>(
        x, W0, Y, N0, dis0, nullptr, nullptr, nullptr, nullptr, nullptr, 0, 1);
    gather128_kernel<<<G((long long)N0 * 64), B, 0, stream>>>(rp0, src0, Y, dis0, b0, H0, N0);

    // ---- pool1 ----
    gatherP_kernel<<<G((long long)N1 * 64), B, 0, stream>>>(pp1, child1, H0, P, N1);
    mm128_kernel<<<G64(N1), B, 0, stream>>>(
        P, pW, X1, N1, nullptr, nullptr, nullptr, pb, bnscale, bnshift, 1, 0);

    // ---- gcn1 ----
    mm128_kernel<<<G64(N1), B, 0, stream>>>(
        X1, W1, Y, N1, dis1, nullptr, nullptr, nullptr, nullptr, nullptr, 0, 0);
    gather128_kernel<<<G((long long)N1 * 64), B, 0, stream>>>(rp1, src1, Y, dis1, b1, H1, N1);

    // ---- pool2 ----
    gatherP_kernel<<<G((long long)N2 * 64), B, 0, stream>>>(pp2, child2, H1, P, N2);
    mm128_kernel<<<G64(N2), B, 0, stream>>>(
        P, pW + 128 * 128, X2, N2, nullptr, nullptr, nullptr, pb + 128, bnscale + 128, bnshift + 128, 1, 0);

    // ---- gcn2 ----
    mm128_kernel<<<G64(N2), B, 0, stream>>>(
        X2, W2, Y, N2, dis2, nullptr, nullptr, nullptr, nullptr, nullptr, 0, 0);
    gather128_kernel<<<G((long long)N2 * 64), B, 0, stream>>>(rp2, src2, Y, dis2, b2, H2, N2);

    // ---- up level 2 ----
    mm128_kernel<<<G64(N2), B, 0, stream>>>(
        H2, pW + 2 * 128 * 128, U2, N2, nullptr, nullptr, nullptr, pb + 256, bnscale + 256, bnshift + 256, 1, 0);
    mm128_kernel<<<G64(N2), B, 0, stream>>>(
        U2, W3, V2, N2, nullptr, nullptr, nullptr, nullptr, nullptr, nullptr, 0, 0);

    // ---- gcn3 ----
    mm128_kernel<<<G64(N1), B, 0, stream>>>(
        H1, W3 + 128 * 128, Y, N1, dis1, V2, parent2, nullptr, nullptr, nullptr, 0, 0);
    gather128_kernel<<<G((long long)N1 * 64), B, 0, stream>>>(rp1, src1, Y, dis1, b3, HU1, N1);

    // ---- up level 1 ----
    mm128_kernel<<<G64(N1), B, 0, stream>>>(
        HU1, pW + 3 * 128 * 128, U1, N1, nullptr, nullptr, nullptr, pb + 384, bnscale + 384, bnshift + 384, 1, 0);
    mm10_kernel<<<G(N1), B, 0, stream>>>(U1, W4, W1b, N1);

    // ---- gcn4: y4p = bf16(dis0 * (w1b[parent1] + h0 @ W4_bot)); gather + log_softmax ----
    mm10p_kernel<<<G(N0), B, 0, stream>>>(H0, W4 + 128 * 10, Y4p, N0, dis0, W1b, parent1);
    gather10_lsm_kernel<<<G(N0), B, 0, stream>>>(rp0, src0, Y4p, dis0, b4, out, N0);
}